// Round 7
// baseline (544.376 us; speedup 1.0000x reference)
//
#include <hip/hip_runtime.h>
#include <cstdint>
#include <cstddef>

#define BB 128
#define TT 512
#define DD 100
#define HH 100
#define NG 400   // 4*H
#define LL 25
#define F_LOG2E 1.44269504088896340736f
#define F_LN2   0.69314718055994530942f

typedef __decltype(__builtin_amdgcn_cvt_pkrtz(0.f, 0.f)) h2_t;
typedef _Float16 v8h __attribute__((ext_vector_type(8)));
typedef float v4f __attribute__((ext_vector_type(4)));

__device__ __forceinline__ h2_t bc_h2(unsigned int u) {
  return __builtin_bit_cast(h2_t, u);
}
__device__ __forceinline__ unsigned int pk(float x, float y) {
  return __builtin_bit_cast(unsigned int, __builtin_amdgcn_cvt_pkrtz(x, y));
}

__device__ __forceinline__ float fdot2(h2_t a, h2_t b, float c) {
#if __has_builtin(__builtin_amdgcn_fdot2)
  return __builtin_amdgcn_fdot2(a, b, c, false);
#else
  return c + (float)a[0] * (float)b[0] + (float)a[1] * (float)b[1];
#endif
}

__device__ __forceinline__ float fexp2(float x) { return __builtin_amdgcn_exp2f(x); }
__device__ __forceinline__ float flog2(float x) { return __builtin_amdgcn_logf(x); }
__device__ __forceinline__ float frcp(float x)  { return __builtin_amdgcn_rcpf(x); }

__device__ __forceinline__ float sigmoid_f(float x) {
  return frcp(1.f + fexp2(-F_LOG2E * x));
}
__device__ __forceinline__ float tanh_f(float x) {
  float e = fexp2(2.f * F_LOG2E * x);
  return 1.f - 2.f * frcp(e + 1.f);
}

// DPP helpers. quad_perm[1,0,3,2]=177 (pair swap); [2,3,0,1]=78; bcast lane2=0xAA.
template <int CTRL>
__device__ __forceinline__ float dppmov(float v) {
#if __has_builtin(__builtin_amdgcn_mov_dpp)
  int m = __builtin_amdgcn_mov_dpp(__builtin_bit_cast(int, v), CTRL, 0xF, 0xF, true);
  return __builtin_bit_cast(float, m);
#else
  return __shfl_xor(v, (CTRL == 177) ? 1 : 2);
#endif
}
template <int CTRL>
__device__ __forceinline__ float qadd(float v) { return v + dppmov<CTRL>(v); }

__device__ __forceinline__ float bperm(float v, int byteidx) {
  return __builtin_bit_cast(float,
      __builtin_amdgcn_ds_bpermute(byteidx, __builtin_bit_cast(int, v)));
}
__device__ __forceinline__ float rfl(float v) {
  return __builtin_bit_cast(float,
      __builtin_amdgcn_readfirstlane(__builtin_bit_cast(int, v)));
}

// LDS-visibility-only barrier (vmcnt left free): imm 0xC07F.
__device__ __forceinline__ void lds_barrier() {
  __builtin_amdgcn_s_waitcnt(0xC07F);
  __builtin_amdgcn_s_barrier();
}

// ---------------------------------------------------------------------------
// gin via MFMA (unchanged layout: ushort position p <-> gate (p&3)*100+(p>>2);
// the new scan reads dword (2j+s) = halves (gate 2s*100+j, (2s+1)*100+j)).
// ---------------------------------------------------------------------------
__global__ __launch_bounds__(256, 1) void gin_mfma(
    const int* __restrict__ tok, const float* __restrict__ emb,
    const float* __restrict__ w_ih_f, const float* __restrict__ b_ih_f,
    const float* __restrict__ b_hh_f,
    const float* __restrict__ w_ih_b, const float* __restrict__ b_ih_b,
    const float* __restrict__ b_hh_b,
    unsigned short* __restrict__ gin16)
{
  const int tid = threadIdx.x;
  const int dir = blockIdx.x & 1;
  const int rb  = blockIdx.x >> 1;
  const int b   = rb >> 1;
  const int t0  = (rb & 1) * 256;

  const float* w_ih = dir ? w_ih_b : w_ih_f;
  const float* b_ih = dir ? b_ih_b : b_ih_f;
  const float* b_hh = dir ? b_hh_b : b_hh_f;

  __shared__ __align__(16) unsigned int wlds[400 * 68];
  __shared__ float bias_l[400];

  for (int i = tid; i < 400 * 68; i += 256) {
    int p = i / 68;
    int d = i - p * 68;
    int r = (p & 3) * 100 + (p >> 2);
    unsigned int v = 0u;
    if (d < 50) {
      const float* wr = w_ih + (size_t)r * DD + 2 * d;
      v = pk(wr[0], wr[1]);
    }
    wlds[i] = v;
  }
  for (int i = tid; i < 400; i += 256) {
    int r = (i & 3) * 100 + (i >> 2);
    bias_l[i] = b_ih[r] + b_hh[r];
  }

  const int wv   = tid >> 6;
  const int lane = tid & 63;
  const int l16  = lane & 15;
  const int quad = lane >> 4;

  v8h af[4][4];
#pragma unroll
  for (int rg = 0; rg < 4; ++rg) {
    int mrow = wv * 64 + rg * 16 + l16;
    int tk = tok[b * TT + t0 + mrow];
    const float* xr = emb + (size_t)tk * DD;
    const int kb = quad * 8;
#pragma unroll
    for (int f = 0; f < 4; ++f) {
      uint4 u;
      if (f < 3) {
        const float* xp = xr + f * 32 + kb;
        float4 va = *(const float4*)(xp);
        float4 vb = *(const float4*)(xp + 4);
        u.x = pk(va.x, va.y); u.y = pk(va.z, va.w);
        u.z = pk(vb.x, vb.y); u.w = pk(vb.z, vb.w);
      } else {
        float4 va = *(const float4*)(xr + 96);
        u.x = pk(va.x, va.y); u.y = pk(va.z, va.w);
        u.z = 0u; u.w = 0u;
      }
      af[rg][f] = __builtin_bit_cast(v8h, u);
    }
  }
  __syncthreads();

  const size_t chbase = ((size_t)(b * 2 + dir) * TT + t0) * NG;
  for (int c = 0; c < 25; ++c) {
    v8h bf[4];
    const unsigned int* wp = wlds + (16 * c + l16) * 68 + quad * 4;
#pragma unroll
    for (int f = 0; f < 4; ++f)
      bf[f] = __builtin_bit_cast(v8h, *(const uint4*)(wp + f * 16));
    float bias_v = bias_l[16 * c + l16];
#pragma unroll
    for (int rg = 0; rg < 4; ++rg) {
      v4f acc = {0.f, 0.f, 0.f, 0.f};
#pragma unroll
      for (int f = 0; f < 4; ++f)
        acc = __builtin_amdgcn_mfma_f32_16x16x32_f16(af[rg][f], bf[f], acc, 0, 0, 0);
      unsigned short* op = gin16 + chbase
          + (size_t)(wv * 64 + rg * 16 + quad * 4) * NG + 16 * c + l16;
#pragma unroll
      for (int r = 0; r < 4; ++r) {
        op[0] = __builtin_bit_cast(unsigned short, (__fp16)(acc[r] + bias_v));
        op += NG;
      }
    }
  }
}

// ---------------------------------------------------------------------------
// LSTM scan v7: pair-split. 320 threads = 5 waves per (batch, dir) block.
// Waves 0-3: 200 unit lanes. Lane = (unit j, K-half s). Per step:
//   one gin dword (2 gates' preacts, depth-2 prefetch), 4 gates x 25 fdot2
//   over the lane's h-half, 4 DPP pair-adds -> full gate sums in both lanes,
//   lane activates its 2 gates (s=0: i,f sig; s=1: g tanh, o sig), 1 DPP
//   pair swap, redundant c update, quad-lane0 packs+writes h dword to LDS.
// Wave 4: 50 emission lanes (label x half), one step behind, f32 stores.
// h LDS layout padded: half0 = dwords[0..24], half1 = dwords[28..52] (16B
// aligned slices); pads zeroed once.
// ---------------------------------------------------------------------------
__global__ __launch_bounds__(320, 2) void lstm_scan7(
    const unsigned short* __restrict__ gin16,
    const float* __restrict__ w_hh_f, const float* __restrict__ w_hh_b,
    const float* __restrict__ w_tag, const float* __restrict__ b_tag,
    float* __restrict__ em_f, float* __restrict__ em_b)
{
  const int tid = threadIdx.x;
  const int b   = blockIdx.x & 127;
  const int dir = blockIdx.x >> 7;
  const float* w_hh = dir ? w_hh_b : w_hh_f;

  __shared__ __align__(16) unsigned int hls0[56];
  __shared__ __align__(16) unsigned int hls1[56];

  const int w = tid >> 6;
  const int i = tid & 63;
  const int basej = (w >> 1) * 50 + (w & 1) * 26;   // 0,26,50,76
  const int cnt2  = (w & 1) ? 48 : 52;
  const bool act_u = (tid < 256) && (i < cnt2);
  const int j = basej + (i >> 1);
  const int s = i & 1;
  const int soff = s ? 28 : 0;

  // unit weights: 4 gates x 25 h2 over K-half s
  h2_t w0[25], w1[25], w2[25], w3[25];
  if (act_u) {
    const float* r0 = w_hh + (size_t)(0 * 100 + j) * HH + 50 * s;
    const float* r1 = w_hh + (size_t)(1 * 100 + j) * HH + 50 * s;
    const float* r2 = w_hh + (size_t)(2 * 100 + j) * HH + 50 * s;
    const float* r3 = w_hh + (size_t)(3 * 100 + j) * HH + 50 * s;
#pragma unroll
    for (int d = 0; d < 25; ++d) {
      w0[d] = __builtin_amdgcn_cvt_pkrtz(r0[2 * d], r0[2 * d + 1]);
      w1[d] = __builtin_amdgcn_cvt_pkrtz(r1[2 * d], r1[2 * d + 1]);
      w2[d] = __builtin_amdgcn_cvt_pkrtz(r2[2 * d], r2[2 * d + 1]);
      w3[d] = __builtin_amdgcn_cvt_pkrtz(r3[2 * d], r3[2 * d + 1]);
    }
  }
  // activation constants for the lane's low gate (s=0: i sigmoid; s=1: g tanh)
  const float kk2 = s ? (2.f * F_LOG2E) : (-F_LOG2E);
  const float cAc = s ? -2.f : 1.f;
  const float cBc = s ? 1.f : 0.f;
  // h write slot (quad-lane0 only)
  const int hd = j >> 1;
  const int hidx = hd + ((hd >= 25) ? 3 : 0);

  // emission lanes: wave 4
  const int ei = tid - 256;
  const bool act_e = (tid >= 256) && (ei < 50);
  const int l  = (ei >= 0) ? (ei >> 1) : 0;
  const int hf = (ei >= 0) ? (ei & 1) : 0;
  const int eoff = hf ? 28 : 0;
  h2_t wt[25];
  float bt = 0.f;
  if (act_e) {
    const float* wr = w_tag + (size_t)l * 200 + dir * 100 + 50 * hf;
#pragma unroll
    for (int d = 0; d < 25; ++d)
      wt[d] = __builtin_amdgcn_cvt_pkrtz(wr[2 * d], wr[2 * d + 1]);
    if (dir == 0 && hf == 0) bt = b_tag[l];
  }
  float* emo = dir ? em_b : em_f;
  float* emp = emo + ((size_t)b * TT + (dir ? (TT - 1) : 0)) * LL + l;
  const ptrdiff_t estep = dir ? -(ptrdiff_t)LL : (ptrdiff_t)LL;

  if (tid < 56) { hls0[tid] = 0u; hls1[tid] = 0u; }

  // gin: dword index 2j+s; row stride 200 dwords
  const unsigned int* gin32 = (const unsigned int*)gin16;
  const unsigned int* gb = gin32 + (size_t)(b * 2 + dir) * TT * 200 + (2 * j + s);
  const ptrdiff_t stp = dir ? -(ptrdiff_t)200 : (ptrdiff_t)200;
  const unsigned int* pf = gb + (size_t)(dir ? (TT - 3) : 2) * 200;

  float c = 0.f;
  unsigned int g0 = 0, g1 = 0;
  if (act_u) {
    g0 = gb[(size_t)(dir ? (TT - 1) : 0) * 200];
    g1 = gb[(size_t)(dir ? (TT - 2) : 1) * 200];
  }
  __syncthreads();

#define UDOT(d, hh) \
  p0 = fdot2(w0[d], bc_h2(hh), p0); p1 = fdot2(w1[d], bc_h2(hh), p1); \
  p2 = fdot2(w2[d], bc_h2(hh), p2); p3 = fdot2(w3[d], bc_h2(hh), p3);
#define EDOT(d, hh) { h2_t h = bc_h2(hh); \
  if ((d & 3) == 0) a0 = fdot2(wt[d], h, a0); \
  else if ((d & 3) == 1) a1 = fdot2(wt[d], h, a1); \
  else if ((d & 3) == 2) a2 = fdot2(wt[d], h, a2); \
  else a3 = fdot2(wt[d], h, a3); }

#define SCAN_STEP(HRD, HWR, TVNZ)                                          \
  {                                                                        \
    if (act_u) {                                                           \
      unsigned int g2 = *pf; pf += stp;                                    \
      const unsigned int* hb = (HRD) + soff;                               \
      uint4 u0 = *((const uint4*)hb);                                      \
      uint4 u1 = *((const uint4*)(hb + 4));                                \
      uint4 u2 = *((const uint4*)(hb + 8));                                \
      uint4 u3 = *((const uint4*)(hb + 12));                               \
      uint4 u4 = *((const uint4*)(hb + 16));                               \
      uint4 u5 = *((const uint4*)(hb + 20));                               \
      unsigned int u24 = hb[24];                                           \
      float p0, p1, p2, p3;                                                \
      p0 = fdot2(w0[0], bc_h2(u0.x), 0.f);                                 \
      p1 = fdot2(w1[0], bc_h2(u0.x), 0.f);                                 \
      p2 = fdot2(w2[0], bc_h2(u0.x), 0.f);                                 \
      p3 = fdot2(w3[0], bc_h2(u0.x), 0.f);                                 \
      UDOT(1, u0.y)  UDOT(2, u0.z)  UDOT(3, u0.w)                          \
      UDOT(4, u1.x)  UDOT(5, u1.y)  UDOT(6, u1.z)  UDOT(7, u1.w)           \
      UDOT(8, u2.x)  UDOT(9, u2.y)  UDOT(10, u2.z) UDOT(11, u2.w)          \
      UDOT(12, u3.x) UDOT(13, u3.y) UDOT(14, u3.z) UDOT(15, u3.w)          \
      UDOT(16, u4.x) UDOT(17, u4.y) UDOT(18, u4.z) UDOT(19, u4.w)          \
      UDOT(20, u5.x) UDOT(21, u5.y) UDOT(22, u5.z) UDOT(23, u5.w)          \
      UDOT(24, u24)                                                        \
      p0 = qadd<177>(p0);                                                  \
      p1 = qadd<177>(p1);                                                  \
      p2 = qadd<177>(p2);                                                  \
      p3 = qadd<177>(p3);                                                  \
      h2_t gg = bc_h2(g0);                                                 \
      float pA = s ? p2 : p0;                                              \
      float pB = s ? p3 : p1;                                              \
      float gateL = pA + (float)gg[0];                                     \
      float gateH = pB + (float)gg[1];                                     \
      float yL = fexp2(kk2 * gateL);                                       \
      float rrL = frcp(1.f + yL);                                          \
      float aL = fmaf(cAc, rrL, cBc);                                      \
      float yH = fexp2(-F_LOG2E * gateH);                                  \
      float aH = frcp(1.f + yH);                                           \
      float rL = dppmov<177>(aL);                                          \
      float rH = dppmov<177>(aH);                                          \
      float iv = s ? rL : aL;                                              \
      float fv = s ? rH : aH;                                              \
      float gv = s ? aL : rL;                                              \
      float ov = s ? aH : rH;                                              \
      c = fmaf(fv, c, iv * gv);                                            \
      float hvv = ov * tanh_f(c);                                          \
      float hnb = dppmov<0xAA>(hvv);                                       \
      if ((i & 3) == 0) ((unsigned int*)(HWR))[hidx] = pk(hvv, hnb);       \
      g0 = g1; g1 = g2;                                                    \
    } else if (act_e && (TVNZ)) {                                          \
      const unsigned int* hb = (HRD) + eoff;                               \
      uint4 e0 = *((const uint4*)hb);                                      \
      uint4 e1 = *((const uint4*)(hb + 4));                                \
      uint4 e2 = *((const uint4*)(hb + 8));                                \
      uint4 e3 = *((const uint4*)(hb + 12));                               \
      uint4 e4 = *((const uint4*)(hb + 16));                               \
      uint4 e5 = *((const uint4*)(hb + 20));                               \
      unsigned int e24 = hb[24];                                           \
      float a0, a1, a2, a3;                                                \
      a0 = fdot2(wt[0], bc_h2(e0.x), 0.f);                                 \
      a1 = fdot2(wt[1], bc_h2(e0.y), 0.f);                                 \
      a2 = fdot2(wt[2], bc_h2(e0.z), 0.f);                                 \
      a3 = fdot2(wt[3], bc_h2(e0.w), 0.f);                                 \
      EDOT(4, e1.x)  EDOT(5, e1.y)  EDOT(6, e1.z)  EDOT(7, e1.w)           \
      EDOT(8, e2.x)  EDOT(9, e2.y)  EDOT(10, e2.z) EDOT(11, e2.w)          \
      EDOT(12, e3.x) EDOT(13, e3.y) EDOT(14, e3.z) EDOT(15, e3.w)          \
      EDOT(16, e4.x) EDOT(17, e4.y) EDOT(18, e4.z) EDOT(19, e4.w)          \
      EDOT(20, e5.x) EDOT(21, e5.y) EDOT(22, e5.z) EDOT(23, e5.w)          \
      EDOT(24, e24)                                                        \
      float ss = (a0 + a1) + (a2 + a3);                                    \
      float tot = qadd<177>(ss);                                           \
      if (hf == 0) *emp = tot + bt;                                        \
      emp += estep;                                                        \
    }                                                                      \
    lds_barrier();                                                         \
  }

  SCAN_STEP(hls0, hls1, false)
  SCAN_STEP(hls1, hls0, true)
  for (int t = 2; t < TT; t += 2) {
    SCAN_STEP(hls0, hls1, true)
    SCAN_STEP(hls1, hls0, true)
  }
#undef SCAN_STEP
#undef UDOT

  // epilogue: emission for the final h (in hls0 after 512 steps)
  if (act_e) {
    const unsigned int* hb = hls0 + eoff;
    uint4 e0 = *((const uint4*)hb);
    uint4 e1 = *((const uint4*)(hb + 4));
    uint4 e2 = *((const uint4*)(hb + 8));
    uint4 e3 = *((const uint4*)(hb + 12));
    uint4 e4 = *((const uint4*)(hb + 16));
    uint4 e5 = *((const uint4*)(hb + 20));
    unsigned int e24 = hb[24];
    float a0, a1, a2, a3;
    a0 = fdot2(wt[0], bc_h2(e0.x), 0.f);
    a1 = fdot2(wt[1], bc_h2(e0.y), 0.f);
    a2 = fdot2(wt[2], bc_h2(e0.z), 0.f);
    a3 = fdot2(wt[3], bc_h2(e0.w), 0.f);
    EDOT(4, e1.x)  EDOT(5, e1.y)  EDOT(6, e1.z)  EDOT(7, e1.w)
    EDOT(8, e2.x)  EDOT(9, e2.y)  EDOT(10, e2.z) EDOT(11, e2.w)
    EDOT(12, e3.x) EDOT(13, e3.y) EDOT(14, e3.z) EDOT(15, e3.w)
    EDOT(16, e4.x) EDOT(17, e4.y) EDOT(18, e4.z) EDOT(19, e4.w)
    EDOT(20, e5.x) EDOT(21, e5.y) EDOT(22, e5.z) EDOT(23, e5.w)
    EDOT(24, e24)
    float ss = (a0 + a1) + (a2 + a3);
    float tot = qadd<177>(ss);
    if (hf == 0) {
      int ttp = dir ? 0 : (TT - 1);
      emo[((size_t)b * TT + ttp) * LL + l] = tot + bt;
    }
  }
#undef EDOT
}

// ---------------------------------------------------------------------------
// FALLBACK scan (small ws): writes hc16 f16.
// ---------------------------------------------------------------------------
__global__ __launch_bounds__(512, 2) void lstm_scan_fb(
    const int* __restrict__ tok, const float* __restrict__ emb,
    const float* __restrict__ w_ih_f, const float* __restrict__ w_hh_f,
    const float* __restrict__ b_ih_f, const float* __restrict__ b_hh_f,
    const float* __restrict__ w_ih_b, const float* __restrict__ w_hh_b,
    const float* __restrict__ b_ih_b, const float* __restrict__ b_hh_b,
    unsigned short* __restrict__ hc16)
{
  const int tid = threadIdx.x;
  const int b   = blockIdx.x & 127;
  const int dir = blockIdx.x >> 7;

  const float* w_ih = dir ? w_ih_b : w_ih_f;
  const float* w_hh = dir ? w_hh_b : w_hh_f;
  const float* b_ih = dir ? b_ih_b : b_ih_f;
  const float* b_hh = dir ? b_hh_b : b_hh_f;

  __shared__ __align__(16) unsigned int xs[2][64];
  __shared__ __align__(16) unsigned int hls[64];
  __shared__ float gl[NG];

  h2_t wih[50], whh[50];
  float bias = 0.f;
  if (tid < NG) {
    const float4* wi = (const float4*)(w_ih + tid * DD);
    const float4* wh = (const float4*)(w_hh + tid * DD);
#pragma unroll
    for (int kk = 0; kk < 25; ++kk) {
      float4 a = wi[kk];
      wih[2 * kk]     = __builtin_amdgcn_cvt_pkrtz(a.x, a.y);
      wih[2 * kk + 1] = __builtin_amdgcn_cvt_pkrtz(a.z, a.w);
      float4 c = wh[kk];
      whh[2 * kk]     = __builtin_amdgcn_cvt_pkrtz(c.x, c.y);
      whh[2 * kk + 1] = __builtin_amdgcn_cvt_pkrtz(c.z, c.w);
    }
    bias = b_ih[tid] + b_hh[tid];
  }
  if (tid < 2) { xs[0][50 + tid] = 0u; xs[1][50 + tid] = 0u; hls[50 + tid] = 0u; }
  if (tid < 50) hls[tid] = 0u;

  const int base = b * TT;
  if (tid >= 448 && tid < 498) {
    int tt0 = dir ? (TT - 1) : 0;
    int i = tid - 448;
    int tk = tok[base + tt0];
    float2 v = ((const float2*)(emb + (size_t)tk * DD))[i];
    xs[0][i] = pk(v.x, v.y);
  }
  __syncthreads();

  float cst = 0.f;
  unsigned short* hcb = hc16 + (size_t)base * 200 + dir * 100;

  for (int t = 0; t < TT; ++t) {
    const int buf = t & 1;
    const int tt  = dir ? (TT - 1 - t) : t;

    if (tid < NG) {
      float a0 = bias, a1 = 0.f, a2 = 0.f, a3 = 0.f;
      const unsigned int* xp = xs[buf];
#pragma unroll
      for (int g = 0; g < 13; ++g) {
        uint4 u = ((const uint4*)xp)[g];
        const int k = 4 * g;
        a0 = fdot2(wih[k], bc_h2(u.x), a0);
        a1 = fdot2(wih[k + 1], bc_h2(u.y), a1);
        if (k + 2 < 50) a2 = fdot2(wih[k + 2], bc_h2(u.z), a2);
        if (k + 3 < 50) a3 = fdot2(wih[k + 3], bc_h2(u.w), a3);
      }
#pragma unroll
      for (int g = 0; g < 13; ++g) {
        uint4 u = ((const uint4*)hls)[g];
        const int k = 4 * g;
        a0 = fdot2(whh[k], bc_h2(u.x), a0);
        a1 = fdot2(whh[k + 1], bc_h2(u.y), a1);
        if (k + 2 < 50) a2 = fdot2(whh[k + 2], bc_h2(u.z), a2);
        if (k + 3 < 50) a3 = fdot2(whh[k + 3], bc_h2(u.w), a3);
      }
      float accs = (a0 + a1) + (a2 + a3);
      float av = (tid >= 200 && tid < 300) ? tanh_f(accs) : sigmoid_f(accs);
      gl[tid] = av;
    } else if (tid >= 448 && tid < 498 && t < TT - 1) {
      int ttn = dir ? (TT - 2 - t) : (t + 1);
      int i = tid - 448;
      int tk = tok[base + ttn];
      float2 v = ((const float2*)(emb + (size_t)tk * DD))[i];
      xs[buf ^ 1][i] = pk(v.x, v.y);
    }
    __syncthreads();

    if (tid < HH) {
      float gi = gl[tid], gf = gl[tid + 100], gg = gl[tid + 200], go = gl[tid + 300];
      cst = gf * cst + gi * gg;
      float hv = go * tanh_f(cst);
      __fp16 h16 = (__fp16)hv;
      ((__fp16*)hls)[tid] = h16;
      hcb[(size_t)tt * 200 + tid] = __builtin_bit_cast(unsigned short, h16);
    }
    __syncthreads();
  }
}

// Fallback emissions kernel.
__global__ __launch_bounds__(256, 2) void emis2(
    const unsigned short* __restrict__ hc16, const float* __restrict__ w_tag,
    const float* __restrict__ b_tag, float* __restrict__ em)
{
  __shared__ unsigned int hsh[64 * 101];
  __shared__ unsigned int wsh[25 * 100];
  const int tid = threadIdx.x;
  const size_t m0 = (size_t)blockIdx.x * 64;

  const unsigned int* hcu = (const unsigned int*)hc16;
  for (int i = tid; i < 64 * 100; i += 256) {
    int r = i / 100;
    int k = i - r * 100;
    hsh[r * 101 + k] = hcu[m0 * 100 + i];
  }
  for (int i = tid; i < 25 * 100; i += 256) {
    float2 wv = ((const float2*)w_tag)[i];
    wsh[i] = pk(wv.x, wv.y);
  }
  __syncthreads();

  const int r = tid & 63, q = tid >> 6;
  int lidx[7];
  bool lv[7];
  float acc[7];
#pragma unroll
  for (int ii = 0; ii < 7; ++ii) {
    int l = q + 4 * ii;
    lv[ii] = (l < LL);
    lidx[ii] = lv[ii] ? l : 0;
    acc[ii] = lv[ii] ? b_tag[lidx[ii]] : 0.f;
  }
  const unsigned int* hrow = hsh + r * 101;
#pragma unroll 2
  for (int k = 0; k < 100; ++k) {
    h2_t hv = bc_h2(hrow[k]);
#pragma unroll
    for (int ii = 0; ii < 7; ++ii)
      acc[ii] = fdot2(hv, bc_h2(wsh[lidx[ii] * 100 + k]), acc[ii]);
  }
#pragma unroll
  for (int ii = 0; ii < 7; ++ii)
    if (lv[ii]) em[(m0 + r) * LL + lidx[ii]] = acc[ii];
}

// ---------------------------------------------------------------------------
// CRF: matvec scan, ONE exp per lane per step, depth-2 em prefetch.
// ---------------------------------------------------------------------------
__global__ __launch_bounds__(128) void crf_scan5(
    const float* __restrict__ em_f, const float* __restrict__ em_b,
    const int* __restrict__ tags, const int* __restrict__ lengths,
    const float* __restrict__ trans,
    const float* __restrict__ startt, const float* __restrict__ endt,
    float* __restrict__ ab, float* __restrict__ gold)
{
  const int tid  = threadIdx.x;
  const int b    = blockIdx.x >> 1;
  const int side = blockIdx.x & 1;

  if (tid < 64) {
    const int lane = tid;
    const int j = (lane < LL) ? lane : 0;
    const float* ef = em_f + (size_t)b * TT * LL;
    const float* eb = em_b + (size_t)b * TT * LL;

    float E[LL];
#pragma unroll
    for (int i = 0; i < LL; ++i) {
      float tv = (side == 0 ? trans[i * LL + j] : trans[j * LL + i]);
      E[i] = fexp2(tv * F_LOG2E);
    }

    float a, C = 0.f;
    if (side == 0) {
      a = (startt[j] + ef[j] + eb[j]) * F_LOG2E;
      float efA = ef[LL + j],     ebA = eb[LL + j];
      float efB = ef[2 * LL + j], ebB = eb[2 * LL + j];
      for (int t = 1; t < 256; ++t) {
        float em2 = (efA + ebA) * F_LOG2E;
        int tn = (t + 2 < 256) ? (t + 2) : 255;
        efA = efB; ebA = ebB;
        efB = ef[(size_t)tn * LL + j];
        ebB = eb[(size_t)tn * LL + j];
        float sh = rfl(a);
        C += sh;
        float A = fexp2(a - sh);
        float s0 = 0.f, s1 = 0.f, s2 = 0.f, s3 = 0.f;
#pragma unroll
        for (int i = 0; i < LL; ++i) {
          float Ai = bperm(A, 4 * i);
          if ((i & 3) == 0) s0 = fmaf(Ai, E[i], s0);
          else if ((i & 3) == 1) s1 = fmaf(Ai, E[i], s1);
          else if ((i & 3) == 2) s2 = fmaf(Ai, E[i], s2);
          else s3 = fmaf(Ai, E[i], s3);
        }
        a = flog2((s0 + s1) + (s2 + s3)) + em2;
      }
    } else {
      a = endt[j] * F_LOG2E;
      float efA = ef[(size_t)(TT - 1) * LL + j], ebA = eb[(size_t)(TT - 1) * LL + j];
      float efB = ef[(size_t)(TT - 2) * LL + j], ebB = eb[(size_t)(TT - 2) * LL + j];
      for (int stpi = 0; stpi < 256; ++stpi) {
        float em2 = (efA + ebA) * F_LOG2E;
        int t1n = (stpi + 2 < 256) ? (TT - 3 - stpi) : 256;
        efA = efB; ebA = ebB;
        efB = ef[(size_t)t1n * LL + j];
        ebB = eb[(size_t)t1n * LL + j];
        float v = a + em2;
        float sh = rfl(v);
        C += sh;
        float A = fexp2(v - sh);
        float s0 = 0.f, s1 = 0.f, s2 = 0.f, s3 = 0.f;
#pragma unroll
        for (int i = 0; i < LL; ++i) {
          float Ai = bperm(A, 4 * i);
          if ((i & 3) == 0) s0 = fmaf(Ai, E[i], s0);
          else if ((i & 3) == 1) s1 = fmaf(Ai, E[i], s1);
          else if ((i & 3) == 2) s2 = fmaf(Ai, E[i], s2);
          else s3 = fmaf(Ai, E[i], s3);
        }
        a = flog2((s0 + s1) + (s2 + s3));
      }
    }
    if (lane < LL)
      ab[((size_t)b * 2 + side) * LL + lane] = (a + C) * F_LN2;
  } else if (side == 0) {
    const int lane = tid - 64;
    const int len = lengths[b];
    float acc = 0.f;
#pragma unroll
    for (int k = 0; k < 8; ++k) {
      int t = k * 64 + lane;
      int tg = tags[b * TT + t];
      size_t ei = ((size_t)b * TT + t) * LL + tg;
      float e = em_f[ei] + em_b[ei];
      float term;
      if (t == 0) term = startt[tg] + e;
      else        term = trans[tags[b * TT + t - 1] * LL + tg] + e;
      if (t == len - 1) term += endt[tg];
      if (t < len) acc += term;
    }
    for (int o = 32; o > 0; o >>= 1) acc += __shfl_down(acc, o);
    if (lane == 0) gold[b] = acc;
  }
}

// ---------------------------------------------------------------------------
// Final: logZ_b = lse(alpha+beta), out = sum_b (logZ_b - gold_b)
// ---------------------------------------------------------------------------
__global__ __launch_bounds__(128, 4) void crf_final(
    const float* __restrict__ ab, const float* __restrict__ gold,
    float* __restrict__ out)
{
  const int b = threadIdx.x;
  float v[LL];
  float m = -1e30f;
#pragma unroll
  for (int l = 0; l < LL; ++l) {
    v[l] = ab[((size_t)b * 2) * LL + l] + ab[((size_t)b * 2 + 1) * LL + l];
    m = fmaxf(m, v[l]);
  }
  float sacc = 0.f;
#pragma unroll
  for (int l = 0; l < LL; ++l) sacc += fexp2((v[l] - m) * F_LOG2E);
  float nll = (m + flog2(sacc) * F_LN2) - gold[b];

  for (int o = 32; o > 0; o >>= 1) nll += __shfl_down(nll, o);
  __shared__ float r2[2];
  if ((b & 63) == 0) r2[b >> 6] = nll;
  __syncthreads();
  if (b == 0) out[0] = r2[0] + r2[1];
}

extern "C" void kernel_launch(void* const* d_in, const int* in_sizes, int n_in,
                              void* d_out, int out_size, void* d_ws, size_t ws_size,
                              hipStream_t stream) {
  const int*   tok   = (const int*)d_in[0];
  const int*   tags  = (const int*)d_in[1];
  const int*   lens  = (const int*)d_in[2];
  const float* emb   = (const float*)d_in[3];
  const float* wif   = (const float*)d_in[4];
  const float* whf   = (const float*)d_in[5];
  const float* bif   = (const float*)d_in[6];
  const float* bhf   = (const float*)d_in[7];
  const float* wib   = (const float*)d_in[8];
  const float* whb   = (const float*)d_in[9];
  const float* bib   = (const float*)d_in[10];
  const float* bhb   = (const float*)d_in[11];
  const float* wtag  = (const float*)d_in[12];
  const float* btag  = (const float*)d_in[13];
  const float* trans = (const float*)d_in[14];
  const float* st    = (const float*)d_in[15];
  const float* en    = (const float*)d_in[16];

  char* wsb = (char*)d_ws;
  float* em_f = (float*)wsb;                                   //  6,553,600 B
  float* em_b = (float*)(wsb + 6553600);                       //  6,553,600 B
  float* gold = (float*)(wsb + 13107200);                      //        512 B
  float* ab   = (float*)(wsb + 13107712);                      //     25,600 B
  unsigned short* gin16 = (unsigned short*)(wsb + 13133312);   // 104,857,600 B
  const size_t need = 117990912ULL;

  if (ws_size >= need) {
    gin_mfma<<<512, 256, 0, stream>>>(tok, emb, wif, bif, bhf, wib, bib, bhb, gin16);
    lstm_scan7<<<256, 320, 0, stream>>>(gin16, whf, whb, wtag, btag, em_f, em_b);
  } else {
    unsigned short* hc16 = (unsigned short*)(wsb + 13133312);
    hipMemsetAsync(em_b, 0, 6553600, stream);
    lstm_scan_fb<<<256, 512, 0, stream>>>(tok, emb, wif, whf, bif, bhf,
                                          wib, whb, bib, bhb, hc16);
    emis2<<<1024, 256, 0, stream>>>(hc16, wtag, btag, em_f);
  }
  crf_scan5<<<256, 128, 0, stream>>>(em_f, em_b, tags, lens, trans, st, en, ab, gold);
  crf_final<<<1, 128, 0, stream>>>(ab, gold, (float*)d_out);
}

// Round 8
// 527.638 us; speedup vs baseline: 1.0317x; 1.0317x over previous
//
#include <hip/hip_runtime.h>
#include <cstdint>
#include <cstddef>

#define BB 128
#define TT 512
#define DD 100
#define HH 100
#define NG 400   // 4*H
#define LL 25
#define F_LOG2E 1.44269504088896340736f
#define F_LN2   0.69314718055994530942f

typedef __decltype(__builtin_amdgcn_cvt_pkrtz(0.f, 0.f)) h2_t;
typedef _Float16 v8h __attribute__((ext_vector_type(8)));
typedef float v4f __attribute__((ext_vector_type(4)));

__device__ __forceinline__ h2_t bc_h2(unsigned int u) {
  return __builtin_bit_cast(h2_t, u);
}
__device__ __forceinline__ unsigned int pk(float x, float y) {
  return __builtin_bit_cast(unsigned int, __builtin_amdgcn_cvt_pkrtz(x, y));
}

__device__ __forceinline__ float fdot2(h2_t a, h2_t b, float c) {
#if __has_builtin(__builtin_amdgcn_fdot2)
  return __builtin_amdgcn_fdot2(a, b, c, false);
#else
  return c + (float)a[0] * (float)b[0] + (float)a[1] * (float)b[1];
#endif
}

__device__ __forceinline__ float fexp2(float x) { return __builtin_amdgcn_exp2f(x); }
__device__ __forceinline__ float flog2(float x) { return __builtin_amdgcn_logf(x); }
__device__ __forceinline__ float frcp(float x)  { return __builtin_amdgcn_rcpf(x); }

__device__ __forceinline__ float sigmoid_f(float x) {
  return frcp(1.f + fexp2(-F_LOG2E * x));
}
__device__ __forceinline__ float tanh_f(float x) {
  float e = fexp2(2.f * F_LOG2E * x);
  return 1.f - 2.f * frcp(e + 1.f);
}

// quad all-reduce add via DPP. xor1 = quad_perm[1,0,3,2] = 177; xor2 = 78.
template <int CTRL>
__device__ __forceinline__ float qadd(float v) {
#if __has_builtin(__builtin_amdgcn_mov_dpp)
  int m = __builtin_amdgcn_mov_dpp(__builtin_bit_cast(int, v), CTRL, 0xF, 0xF, true);
  return v + __builtin_bit_cast(float, m);
#else
  int x = (CTRL == 177) ? 1 : 2;
  return v + __shfl_xor(v, x);
#endif
}

// quad broadcast of lane LANE (0..3) via DPP quad_perm[L,L,L,L].
template <int LANE>
__device__ __forceinline__ float qbcast(float v) {
#if __has_builtin(__builtin_amdgcn_mov_dpp)
  int m = __builtin_amdgcn_mov_dpp(__builtin_bit_cast(int, v), LANE * 0x55, 0xF, 0xF, true);
  return __builtin_bit_cast(float, m);
#else
  return __shfl(v, (threadIdx.x & 63 & ~3) + LANE);
#endif
}

__device__ __forceinline__ float bperm(float v, int byteidx) {
  return __builtin_bit_cast(float,
      __builtin_amdgcn_ds_bpermute(byteidx, __builtin_bit_cast(int, v)));
}
__device__ __forceinline__ float rfl(float v) {
  return __builtin_bit_cast(float,
      __builtin_amdgcn_readfirstlane(__builtin_bit_cast(int, v)));
}

// LDS-visibility-only barrier (vmcnt left free): imm 0xC07F.
__device__ __forceinline__ void lds_barrier() {
  __builtin_amdgcn_s_waitcnt(0xC07F);
  __builtin_amdgcn_s_barrier();
}

// ---------------------------------------------------------------------------
// gin via MFMA, v2 (LDS-free). C[m][n] = x[row m] · w_ih[row n] with n in
// NATURAL gate order; the scan's permutation is applied at the STORE address:
// p(n) = 4*(n%100) + n/100  (so gin16 position p holds gate (p&3)*100+(p>>2),
// identical layout to before). B frags load straight from global (w_ih is
// 160 KB -> L2-resident, shared by all 512 blocks). K zero-pad on the B side
// (quad0 partial / quads1-3 zero for k=96..127) annihilates A garbage.
// ---------------------------------------------------------------------------
__global__ __launch_bounds__(256, 2) void gin_mfma2(
    const int* __restrict__ tok, const float* __restrict__ emb,
    const float* __restrict__ w_ih_f, const float* __restrict__ b_ih_f,
    const float* __restrict__ b_hh_f,
    const float* __restrict__ w_ih_b, const float* __restrict__ b_ih_b,
    const float* __restrict__ b_hh_b,
    unsigned short* __restrict__ gin16)
{
  const int tid = threadIdx.x;
  const int dir = blockIdx.x & 1;
  const int rb  = blockIdx.x >> 1;        // 0..255
  const int b   = rb >> 1;
  const int t0  = (rb & 1) * 256;

  const float* w_ih = dir ? w_ih_b : w_ih_f;
  const float* b_ih = dir ? b_ih_b : b_ih_f;
  const float* b_hh = dir ? b_hh_b : b_hh_f;

  const int wv   = tid >> 6;
  const int lane = tid & 63;
  const int l16  = lane & 15;
  const int quad = lane >> 4;

  // A fragments: 4 rowgroups x 4 K-frags, straight from emb (f32 -> f16)
  v8h af[4][4];
#pragma unroll
  for (int rg = 0; rg < 4; ++rg) {
    int mrow = wv * 64 + rg * 16 + l16;
    int tk = tok[b * TT + t0 + mrow];
    const float* xr = emb + (size_t)tk * DD;
    const int kb = quad * 8;
#pragma unroll
    for (int f = 0; f < 4; ++f) {
      uint4 u;
      if (f < 3) {
        const float* xp = xr + f * 32 + kb;
        float4 va = *(const float4*)(xp);
        float4 vb = *(const float4*)(xp + 4);
        u.x = pk(va.x, va.y); u.y = pk(va.z, va.w);
        u.z = pk(vb.x, vb.y); u.w = pk(vb.z, vb.w);
      } else {
        float4 va = *(const float4*)(xr + 96);
        u.x = pk(va.x, va.y); u.y = pk(va.z, va.w);
        u.z = 0u; u.w = 0u;
      }
      af[rg][f] = __builtin_bit_cast(v8h, u);
    }
  }

  const size_t chbase = ((size_t)(b * 2 + dir) * TT + t0) * NG;
  for (int c = 0; c < 25; ++c) {
    const int n = 16 * c + l16;                 // natural gate row
    const float* wr = w_ih + (size_t)n * DD;
    // B fragments: B[k][n] = w_ih[n][k], k = f*32 + quad*8 + j
    v8h bf[4];
#pragma unroll
    for (int f = 0; f < 3; ++f) {
      const float* wp = wr + f * 32 + quad * 8;
      float4 va = *(const float4*)(wp);
      float4 vb = *(const float4*)(wp + 4);
      uint4 u;
      u.x = pk(va.x, va.y); u.y = pk(va.z, va.w);
      u.z = pk(vb.x, vb.y); u.w = pk(vb.z, vb.w);
      bf[f] = __builtin_bit_cast(v8h, u);
    }
    {
      uint4 u = {0u, 0u, 0u, 0u};
      if (quad == 0) {
        float4 va = *(const float4*)(wr + 96);
        u.x = pk(va.x, va.y); u.y = pk(va.z, va.w);
      }
      bf[3] = __builtin_bit_cast(v8h, u);
    }
    float bias_v = b_ih[n] + b_hh[n];
    // store position: p(n) = 4*(n%100) + n/100
    const int qn = (n * 41) >> 12;              // n/100 for n<400
    const int p  = ((n - 100 * qn) << 2) + qn;

#pragma unroll
    for (int rg = 0; rg < 4; ++rg) {
      v4f acc = {0.f, 0.f, 0.f, 0.f};
#pragma unroll
      for (int f = 0; f < 4; ++f)
        acc = __builtin_amdgcn_mfma_f32_16x16x32_f16(af[rg][f], bf[f], acc, 0, 0, 0);
      unsigned short* op = gin16 + chbase
          + (size_t)(wv * 64 + rg * 16 + quad * 4) * NG + p;
#pragma unroll
      for (int r = 0; r < 4; ++r) {
        op[0] = __builtin_bit_cast(unsigned short, (__fp16)(acc[r] + bias_v));
        op += NG;
      }
    }
  }
}

// ---------------------------------------------------------------------------
// LSTM scan v6 (reverted best): one block per (batch, direction), 512 threads.
// Unit lanes (tid<400): (unit j = tid>>2, K-slice s = tid&3); DPP quad
// reduce/bcast; gin prefetch via unconditional pointer walk; 2x unrolled
// explicit LDS double-buffer. Wave 7 = 50 emission lanes.
// ---------------------------------------------------------------------------
__global__ __launch_bounds__(512, 2) void lstm_scan6(
    const unsigned short* __restrict__ gin16,
    const float* __restrict__ w_hh_f, const float* __restrict__ w_hh_b,
    const float* __restrict__ w_tag, const float* __restrict__ b_tag,
    float* __restrict__ em_f, float* __restrict__ em_b)
{
  const int tid = threadIdx.x;
  const int b   = blockIdx.x & 127;
  const int dir = blockIdx.x >> 7;
  const float* w_hh = dir ? w_hh_b : w_hh_f;

  __shared__ __align__(16) unsigned int hls0[52];
  __shared__ __align__(16) unsigned int hls1[52];

  const bool uact = tid < NG;
  const int j = tid >> 2;
  const int s = tid & 3;
  const int od = 12 * s;
  const int nn = (s == 3) ? 14 : 12;

  h2_t wA[14], wB[14], wC[14], wD[14];
  if (uact) {
#pragma unroll
    for (int d = 0; d < 14; ++d) {
      int dd = (d < nn) ? (od + d) : 0;
      const float* r0 = w_hh + (size_t)(0 * 100 + j) * HH + 2 * dd;
      const float* r1 = w_hh + (size_t)(1 * 100 + j) * HH + 2 * dd;
      const float* r2 = w_hh + (size_t)(2 * 100 + j) * HH + 2 * dd;
      const float* r3 = w_hh + (size_t)(3 * 100 + j) * HH + 2 * dd;
      h2_t z = __builtin_amdgcn_cvt_pkrtz(0.f, 0.f);
      wA[d] = (d < nn) ? __builtin_amdgcn_cvt_pkrtz(r0[0], r0[1]) : z;
      wB[d] = (d < nn) ? __builtin_amdgcn_cvt_pkrtz(r1[0], r1[1]) : z;
      wC[d] = (d < nn) ? __builtin_amdgcn_cvt_pkrtz(r2[0], r2[1]) : z;
      wD[d] = (d < nn) ? __builtin_amdgcn_cvt_pkrtz(r3[0], r3[1]) : z;
    }
  }
  const float kk2 = (s == 2) ? (2.f * F_LOG2E) : (-F_LOG2E);
  const float cA  = (s == 2) ? -2.f : 1.f;
  const float cB  = (s == 2) ? 1.f : 0.f;

  const int el = tid - 448;
  const bool eact = (el >= 0) && (el < 50);
  const int l  = (el >= 0) ? (el >> 1) : 0;
  const int hf = (el >= 0) ? (el & 1) : 0;
  const int eo = hf ? 24 : 0;
  const int en = hf ? 26 : 24;
  h2_t wt[26];
  float bt = 0.f;
  if (eact) {
    const float* wr = w_tag + (size_t)l * 200 + dir * 100;
#pragma unroll
    for (int d = 0; d < 26; ++d) {
      int dd = (d < en) ? (eo + d) : 0;
      h2_t z = __builtin_amdgcn_cvt_pkrtz(0.f, 0.f);
      wt[d] = (d < en) ? __builtin_amdgcn_cvt_pkrtz(wr[2 * dd], wr[2 * dd + 1]) : z;
    }
    if (dir == 0 && hf == 0) bt = b_tag[l];
  }
  float* emo = dir ? em_b : em_f;
  float* emp = emo + ((size_t)b * TT + (dir ? (TT - 1) : 0)) * LL + l;
  const ptrdiff_t estep = dir ? -(ptrdiff_t)LL : (ptrdiff_t)LL;

  if (tid < 52) { hls0[tid] = 0u; hls1[tid] = 0u; }

  const unsigned short* gb = gin16 + (size_t)(b * 2 + dir) * TT * NG + tid;
  const ptrdiff_t stp = dir ? -(ptrdiff_t)NG : (ptrdiff_t)NG;
  const unsigned short* pf = gb + (size_t)(dir ? (TT - 3) : 2) * NG;

  float c = 0.f;
  unsigned short g0 = 0, g1 = 0;
  if (uact) {
    g0 = gb[(size_t)(dir ? (TT - 1) : 0) * NG];
    g1 = gb[(size_t)(dir ? (TT - 2) : 1) * NG];
  }
  __syncthreads();

#define SDOT(d, hh) \
  p0 = fdot2(wA[d], bc_h2(hh), p0); p1 = fdot2(wB[d], bc_h2(hh), p1); \
  p2 = fdot2(wC[d], bc_h2(hh), p2); p3 = fdot2(wD[d], bc_h2(hh), p3);
#define EDOT(d, hh) { h2_t h = bc_h2(hh); \
  if ((d & 3) == 0) a0 = fdot2(wt[d], h, a0); \
  else if ((d & 3) == 1) a1 = fdot2(wt[d], h, a1); \
  else if ((d & 3) == 2) a2 = fdot2(wt[d], h, a2); \
  else a3 = fdot2(wt[d], h, a3); }

#define SCAN_STEP(HRD, HWR, TVNZ)                                          \
  {                                                                        \
    if (uact) {                                                            \
      unsigned short g2 = *pf; pf += stp;                                  \
      const unsigned int* hp = (HRD) + od;                                 \
      uint4 u0 = *((const uint4*)hp);                                      \
      uint4 u1 = *((const uint4*)(hp + 4));                                \
      uint4 u2 = *((const uint4*)(hp + 8));                                \
      uint2 u3 = *((const uint2*)(hp + 12));                               \
      float p0, p1, p2, p3;                                                \
      p0 = fdot2(wA[0], bc_h2(u0.x), 0.f);                                 \
      p1 = fdot2(wB[0], bc_h2(u0.x), 0.f);                                 \
      p2 = fdot2(wC[0], bc_h2(u0.x), 0.f);                                 \
      p3 = fdot2(wD[0], bc_h2(u0.x), 0.f);                                 \
      SDOT(1, u0.y)  SDOT(2, u0.z)  SDOT(3, u0.w)                          \
      SDOT(4, u1.x)  SDOT(5, u1.y)  SDOT(6, u1.z)  SDOT(7, u1.w)           \
      SDOT(8, u2.x)  SDOT(9, u2.y)  SDOT(10, u2.z) SDOT(11, u2.w)          \
      SDOT(12, u3.x) SDOT(13, u3.y)                                        \
      p0 = qadd<78>(qadd<177>(p0));                                        \
      p1 = qadd<78>(qadd<177>(p1));                                        \
      p2 = qadd<78>(qadd<177>(p2));                                        \
      p3 = qadd<78>(qadd<177>(p3));                                        \
      float psel = (s == 0) ? p0 : (s == 1) ? p1 : (s == 2) ? p2 : p3;     \
      float gate = psel + (float)__builtin_bit_cast(__fp16, g0);           \
      float y  = fexp2(kk2 * gate);                                        \
      float rr = frcp(1.f + y);                                            \
      float actv = fmaf(cA, rr, cB);                                       \
      float iv = qbcast<0>(actv);                                          \
      float fv = qbcast<1>(actv);                                          \
      float gv = qbcast<2>(actv);                                          \
      float ov = qbcast<3>(actv);                                          \
      c = fmaf(fv, c, iv * gv);                                            \
      float hvv = ov * tanh_f(c);                                          \
      if (s == 0) ((__fp16*)(HWR))[j] = (__fp16)hvv;                       \
      g0 = g1; g1 = g2;                                                    \
    } else if (eact && (TVNZ)) {                                           \
      const unsigned int* hp = (HRD) + eo;                                 \
      uint4 e0 = *((const uint4*)hp);                                      \
      uint4 e1 = *((const uint4*)(hp + 4));                                \
      uint4 e2 = *((const uint4*)(hp + 8));                                \
      uint4 e3 = *((const uint4*)(hp + 12));                               \
      uint4 e4 = *((const uint4*)(hp + 16));                               \
      uint4 e5 = *((const uint4*)(hp + 20));                               \
      uint2 e6 = *((const uint2*)(hp + 24));                               \
      float a0, a1, a2, a3;                                                \
      a0 = fdot2(wt[0], bc_h2(e0.x), 0.f);                                 \
      a1 = fdot2(wt[1], bc_h2(e0.y), 0.f);                                 \
      a2 = fdot2(wt[2], bc_h2(e0.z), 0.f);                                 \
      a3 = fdot2(wt[3], bc_h2(e0.w), 0.f);                                 \
      EDOT(4, e1.x)  EDOT(5, e1.y)  EDOT(6, e1.z)  EDOT(7, e1.w)           \
      EDOT(8, e2.x)  EDOT(9, e2.y)  EDOT(10, e2.z) EDOT(11, e2.w)          \
      EDOT(12, e3.x) EDOT(13, e3.y) EDOT(14, e3.z) EDOT(15, e3.w)          \
      EDOT(16, e4.x) EDOT(17, e4.y) EDOT(18, e4.z) EDOT(19, e4.w)          \
      EDOT(20, e5.x) EDOT(21, e5.y) EDOT(22, e5.z) EDOT(23, e5.w)          \
      EDOT(24, e6.x) EDOT(25, e6.y)                                        \
      float ss = (a0 + a1) + (a2 + a3);                                    \
      float tot = qadd<177>(ss);                                           \
      if (hf == 0) *emp = tot + bt;                                        \
      emp += estep;                                                        \
    }                                                                      \
    lds_barrier();                                                         \
  }

  SCAN_STEP(hls0, hls1, false)
  SCAN_STEP(hls1, hls0, true)
  for (int t = 2; t < TT; t += 2) {
    SCAN_STEP(hls0, hls1, true)
    SCAN_STEP(hls1, hls0, true)
  }
#undef SCAN_STEP
#undef SDOT

  // epilogue: emission for the last h (in hls0 after 512 steps)
  if (eact) {
    const unsigned int* hp = hls0 + eo;
    uint4 e0 = *((const uint4*)hp);
    uint4 e1 = *((const uint4*)(hp + 4));
    uint4 e2 = *((const uint4*)(hp + 8));
    uint4 e3 = *((const uint4*)(hp + 12));
    uint4 e4 = *((const uint4*)(hp + 16));
    uint4 e5 = *((const uint4*)(hp + 20));
    uint2 e6 = *((const uint2*)(hp + 24));
    float a0, a1, a2, a3;
    a0 = fdot2(wt[0], bc_h2(e0.x), 0.f);
    a1 = fdot2(wt[1], bc_h2(e0.y), 0.f);
    a2 = fdot2(wt[2], bc_h2(e0.z), 0.f);
    a3 = fdot2(wt[3], bc_h2(e0.w), 0.f);
    EDOT(4, e1.x)  EDOT(5, e1.y)  EDOT(6, e1.z)  EDOT(7, e1.w)
    EDOT(8, e2.x)  EDOT(9, e2.y)  EDOT(10, e2.z) EDOT(11, e2.w)
    EDOT(12, e3.x) EDOT(13, e3.y) EDOT(14, e3.z) EDOT(15, e3.w)
    EDOT(16, e4.x) EDOT(17, e4.y) EDOT(18, e4.z) EDOT(19, e4.w)
    EDOT(20, e5.x) EDOT(21, e5.y) EDOT(22, e5.z) EDOT(23, e5.w)
    EDOT(24, e6.x) EDOT(25, e6.y)
    float ss = (a0 + a1) + (a2 + a3);
    float tot = qadd<177>(ss);
    if (hf == 0) {
      int ttp = dir ? 0 : (TT - 1);
      emo[((size_t)b * TT + ttp) * LL + l] = tot + bt;
    }
  }
#undef EDOT
}

// ---------------------------------------------------------------------------
// FALLBACK scan (small ws): writes hc16 f16.
// ---------------------------------------------------------------------------
__global__ __launch_bounds__(512, 2) void lstm_scan_fb(
    const int* __restrict__ tok, const float* __restrict__ emb,
    const float* __restrict__ w_ih_f, const float* __restrict__ w_hh_f,
    const float* __restrict__ b_ih_f, const float* __restrict__ b_hh_f,
    const float* __restrict__ w_ih_b, const float* __restrict__ w_hh_b,
    const float* __restrict__ b_ih_b, const float* __restrict__ b_hh_b,
    unsigned short* __restrict__ hc16)
{
  const int tid = threadIdx.x;
  const int b   = blockIdx.x & 127;
  const int dir = blockIdx.x >> 7;

  const float* w_ih = dir ? w_ih_b : w_ih_f;
  const float* w_hh = dir ? w_hh_b : w_hh_f;
  const float* b_ih = dir ? b_ih_b : b_ih_f;
  const float* b_hh = dir ? b_hh_b : b_hh_f;

  __shared__ __align__(16) unsigned int xs[2][64];
  __shared__ __align__(16) unsigned int hls[64];
  __shared__ float gl[NG];

  h2_t wih[50], whh[50];
  float bias = 0.f;
  if (tid < NG) {
    const float4* wi = (const float4*)(w_ih + tid * DD);
    const float4* wh = (const float4*)(w_hh + tid * DD);
#pragma unroll
    for (int kk = 0; kk < 25; ++kk) {
      float4 a = wi[kk];
      wih[2 * kk]     = __builtin_amdgcn_cvt_pkrtz(a.x, a.y);
      wih[2 * kk + 1] = __builtin_amdgcn_cvt_pkrtz(a.z, a.w);
      float4 c = wh[kk];
      whh[2 * kk]     = __builtin_amdgcn_cvt_pkrtz(c.x, c.y);
      whh[2 * kk + 1] = __builtin_amdgcn_cvt_pkrtz(c.z, c.w);
    }
    bias = b_ih[tid] + b_hh[tid];
  }
  if (tid < 2) { xs[0][50 + tid] = 0u; xs[1][50 + tid] = 0u; hls[50 + tid] = 0u; }
  if (tid < 50) hls[tid] = 0u;

  const int base = b * TT;
  if (tid >= 448 && tid < 498) {
    int tt0 = dir ? (TT - 1) : 0;
    int i = tid - 448;
    int tk = tok[base + tt0];
    float2 v = ((const float2*)(emb + (size_t)tk * DD))[i];
    xs[0][i] = pk(v.x, v.y);
  }
  __syncthreads();

  float cst = 0.f;
  unsigned short* hcb = hc16 + (size_t)base * 200 + dir * 100;

  for (int t = 0; t < TT; ++t) {
    const int buf = t & 1;
    const int tt  = dir ? (TT - 1 - t) : t;

    if (tid < NG) {
      float a0 = bias, a1 = 0.f, a2 = 0.f, a3 = 0.f;
      const unsigned int* xp = xs[buf];
#pragma unroll
      for (int g = 0; g < 13; ++g) {
        uint4 u = ((const uint4*)xp)[g];
        const int k = 4 * g;
        a0 = fdot2(wih[k], bc_h2(u.x), a0);
        a1 = fdot2(wih[k + 1], bc_h2(u.y), a1);
        if (k + 2 < 50) a2 = fdot2(wih[k + 2], bc_h2(u.z), a2);
        if (k + 3 < 50) a3 = fdot2(wih[k + 3], bc_h2(u.w), a3);
      }
#pragma unroll
      for (int g = 0; g < 13; ++g) {
        uint4 u = ((const uint4*)hls)[g];
        const int k = 4 * g;
        a0 = fdot2(whh[k], bc_h2(u.x), a0);
        a1 = fdot2(whh[k + 1], bc_h2(u.y), a1);
        if (k + 2 < 50) a2 = fdot2(whh[k + 2], bc_h2(u.z), a2);
        if (k + 3 < 50) a3 = fdot2(whh[k + 3], bc_h2(u.w), a3);
      }
      float accs = (a0 + a1) + (a2 + a3);
      float av = (tid >= 200 && tid < 300) ? tanh_f(accs) : sigmoid_f(accs);
      gl[tid] = av;
    } else if (tid >= 448 && tid < 498 && t < TT - 1) {
      int ttn = dir ? (TT - 2 - t) : (t + 1);
      int i = tid - 448;
      int tk = tok[base + ttn];
      float2 v = ((const float2*)(emb + (size_t)tk * DD))[i];
      xs[buf ^ 1][i] = pk(v.x, v.y);
    }
    __syncthreads();

    if (tid < HH) {
      float gi = gl[tid], gf = gl[tid + 100], gg = gl[tid + 200], go = gl[tid + 300];
      cst = gf * cst + gi * gg;
      float hv = go * tanh_f(cst);
      __fp16 h16 = (__fp16)hv;
      ((__fp16*)hls)[tid] = h16;
      hcb[(size_t)tt * 200 + tid] = __builtin_bit_cast(unsigned short, h16);
    }
    __syncthreads();
  }
}

// Fallback emissions kernel.
__global__ __launch_bounds__(256, 2) void emis2(
    const unsigned short* __restrict__ hc16, const float* __restrict__ w_tag,
    const float* __restrict__ b_tag, float* __restrict__ em)
{
  __shared__ unsigned int hsh[64 * 101];
  __shared__ unsigned int wsh[25 * 100];
  const int tid = threadIdx.x;
  const size_t m0 = (size_t)blockIdx.x * 64;

  const unsigned int* hcu = (const unsigned int*)hc16;
  for (int i = tid; i < 64 * 100; i += 256) {
    int r = i / 100;
    int k = i - r * 100;
    hsh[r * 101 + k] = hcu[m0 * 100 + i];
  }
  for (int i = tid; i < 25 * 100; i += 256) {
    float2 wv = ((const float2*)w_tag)[i];
    wsh[i] = pk(wv.x, wv.y);
  }
  __syncthreads();

  const int r = tid & 63, q = tid >> 6;
  int lidx[7];
  bool lv[7];
  float acc[7];
#pragma unroll
  for (int ii = 0; ii < 7; ++ii) {
    int l = q + 4 * ii;
    lv[ii] = (l < LL);
    lidx[ii] = lv[ii] ? l : 0;
    acc[ii] = lv[ii] ? b_tag[lidx[ii]] : 0.f;
  }
  const unsigned int* hrow = hsh + r * 101;
#pragma unroll 2
  for (int k = 0; k < 100; ++k) {
    h2_t hv = bc_h2(hrow[k]);
#pragma unroll
    for (int ii = 0; ii < 7; ++ii)
      acc[ii] = fdot2(hv, bc_h2(wsh[lidx[ii] * 100 + k]), acc[ii]);
  }
#pragma unroll
  for (int ii = 0; ii < 7; ++ii)
    if (lv[ii]) em[(m0 + r) * LL + lidx[ii]] = acc[ii];
}

// ---------------------------------------------------------------------------
// CRF: matvec scan, ONE exp per lane per step, depth-2 em prefetch.
// ---------------------------------------------------------------------------
__global__ __launch_bounds__(128) void crf_scan5(
    const float* __restrict__ em_f, const float* __restrict__ em_b,
    const int* __restrict__ tags, const int* __restrict__ lengths,
    const float* __restrict__ trans,
    const float* __restrict__ startt, const float* __restrict__ endt,
    float* __restrict__ ab, float* __restrict__ gold)
{
  const int tid  = threadIdx.x;
  const int b    = blockIdx.x >> 1;
  const int side = blockIdx.x & 1;

  if (tid < 64) {
    const int lane = tid;
    const int j = (lane < LL) ? lane : 0;
    const float* ef = em_f + (size_t)b * TT * LL;
    const float* eb = em_b + (size_t)b * TT * LL;

    float E[LL];
#pragma unroll
    for (int i = 0; i < LL; ++i) {
      float tv = (side == 0 ? trans[i * LL + j] : trans[j * LL + i]);
      E[i] = fexp2(tv * F_LOG2E);
    }

    float a, C = 0.f;
    if (side == 0) {
      a = (startt[j] + ef[j] + eb[j]) * F_LOG2E;
      float efA = ef[LL + j],     ebA = eb[LL + j];
      float efB = ef[2 * LL + j], ebB = eb[2 * LL + j];
      for (int t = 1; t < 256; ++t) {
        float em2 = (efA + ebA) * F_LOG2E;
        int tn = (t + 2 < 256) ? (t + 2) : 255;
        efA = efB; ebA = ebB;
        efB = ef[(size_t)tn * LL + j];
        ebB = eb[(size_t)tn * LL + j];
        float sh = rfl(a);
        C += sh;
        float A = fexp2(a - sh);
        float s0 = 0.f, s1 = 0.f, s2 = 0.f, s3 = 0.f;
#pragma unroll
        for (int i = 0; i < LL; ++i) {
          float Ai = bperm(A, 4 * i);
          if ((i & 3) == 0) s0 = fmaf(Ai, E[i], s0);
          else if ((i & 3) == 1) s1 = fmaf(Ai, E[i], s1);
          else if ((i & 3) == 2) s2 = fmaf(Ai, E[i], s2);
          else s3 = fmaf(Ai, E[i], s3);
        }
        a = flog2((s0 + s1) + (s2 + s3)) + em2;
      }
    } else {
      a = endt[j] * F_LOG2E;
      float efA = ef[(size_t)(TT - 1) * LL + j], ebA = eb[(size_t)(TT - 1) * LL + j];
      float efB = ef[(size_t)(TT - 2) * LL + j], ebB = eb[(size_t)(TT - 2) * LL + j];
      for (int stpi = 0; stpi < 256; ++stpi) {
        float em2 = (efA + ebA) * F_LOG2E;
        int t1n = (stpi + 2 < 256) ? (TT - 3 - stpi) : 256;
        efA = efB; ebA = ebB;
        efB = ef[(size_t)t1n * LL + j];
        ebB = eb[(size_t)t1n * LL + j];
        float v = a + em2;
        float sh = rfl(v);
        C += sh;
        float A = fexp2(v - sh);
        float s0 = 0.f, s1 = 0.f, s2 = 0.f, s3 = 0.f;
#pragma unroll
        for (int i = 0; i < LL; ++i) {
          float Ai = bperm(A, 4 * i);
          if ((i & 3) == 0) s0 = fmaf(Ai, E[i], s0);
          else if ((i & 3) == 1) s1 = fmaf(Ai, E[i], s1);
          else if ((i & 3) == 2) s2 = fmaf(Ai, E[i], s2);
          else s3 = fmaf(Ai, E[i], s3);
        }
        a = flog2((s0 + s1) + (s2 + s3));
      }
    }
    if (lane < LL)
      ab[((size_t)b * 2 + side) * LL + lane] = (a + C) * F_LN2;
  } else if (side == 0) {
    const int lane = tid - 64;
    const int len = lengths[b];
    float acc = 0.f;
#pragma unroll
    for (int k = 0; k < 8; ++k) {
      int t = k * 64 + lane;
      int tg = tags[b * TT + t];
      size_t ei = ((size_t)b * TT + t) * LL + tg;
      float e = em_f[ei] + em_b[ei];
      float term;
      if (t == 0) term = startt[tg] + e;
      else        term = trans[tags[b * TT + t - 1] * LL + tg] + e;
      if (t == len - 1) term += endt[tg];
      if (t < len) acc += term;
    }
    for (int o = 32; o > 0; o >>= 1) acc += __shfl_down(acc, o);
    if (lane == 0) gold[b] = acc;
  }
}

// ---------------------------------------------------------------------------
// Final: logZ_b = lse(alpha+beta), out = sum_b (logZ_b - gold_b)
// ---------------------------------------------------------------------------
__global__ __launch_bounds__(128, 4) void crf_final(
    const float* __restrict__ ab, const float* __restrict__ gold,
    float* __restrict__ out)
{
  const int b = threadIdx.x;
  float v[LL];
  float m = -1e30f;
#pragma unroll
  for (int l = 0; l < LL; ++l) {
    v[l] = ab[((size_t)b * 2) * LL + l] + ab[((size_t)b * 2 + 1) * LL + l];
    m = fmaxf(m, v[l]);
  }
  float sacc = 0.f;
#pragma unroll
  for (int l = 0; l < LL; ++l) sacc += fexp2((v[l] - m) * F_LOG2E);
  float nll = (m + flog2(sacc) * F_LN2) - gold[b];

  for (int o = 32; o > 0; o >>= 1) nll += __shfl_down(nll, o);
  __shared__ float r2[2];
  if ((b & 63) == 0) r2[b >> 6] = nll;
  __syncthreads();
  if (b == 0) out[0] = r2[0] + r2[1];
}

extern "C" void kernel_launch(void* const* d_in, const int* in_sizes, int n_in,
                              void* d_out, int out_size, void* d_ws, size_t ws_size,
                              hipStream_t stream) {
  const int*   tok   = (const int*)d_in[0];
  const int*   tags  = (const int*)d_in[1];
  const int*   lens  = (const int*)d_in[2];
  const float* emb   = (const float*)d_in[3];
  const float* wif   = (const float*)d_in[4];
  const float* whf   = (const float*)d_in[5];
  const float* bif   = (const float*)d_in[6];
  const float* bhf   = (const float*)d_in[7];
  const float* wib   = (const float*)d_in[8];
  const float* whb   = (const float*)d_in[9];
  const float* bib   = (const float*)d_in[10];
  const float* bhb   = (const float*)d_in[11];
  const float* wtag  = (const float*)d_in[12];
  const float* btag  = (const float*)d_in[13];
  const float* trans = (const float*)d_in[14];
  const float* st    = (const float*)d_in[15];
  const float* en    = (const float*)d_in[16];

  char* wsb = (char*)d_ws;
  float* em_f = (float*)wsb;                                   //  6,553,600 B
  float* em_b = (float*)(wsb + 6553600);                       //  6,553,600 B
  float* gold = (float*)(wsb + 13107200);                      //        512 B
  float* ab   = (float*)(wsb + 13107712);                      //     25,600 B
  unsigned short* gin16 = (unsigned short*)(wsb + 13133312);   // 104,857,600 B
  const size_t need = 117990912ULL;

  if (ws_size >= need) {
    gin_mfma2<<<512, 256, 0, stream>>>(tok, emb, wif, bif, bhf, wib, bib, bhb, gin16);
    lstm_scan6<<<256, 512, 0, stream>>>(gin16, whf, whb, wtag, btag, em_f, em_b);
  } else {
    unsigned short* hc16 = (unsigned short*)(wsb + 13133312);
    hipMemsetAsync(em_b, 0, 6553600, stream);
    lstm_scan_fb<<<256, 512, 0, stream>>>(tok, emb, wif, whf, bif, bhf,
                                          wib, whb, bib, bhb, hc16);
    emis2<<<1024, 256, 0, stream>>>(hc16, wtag, btag, em_f);
  }
  crf_scan5<<<256, 128, 0, stream>>>(em_f, em_b, tags, lens, trans, st, en, ab, gold);
  crf_final<<<1, 128, 0, stream>>>(ab, gold, (float*)d_out);
}

// Round 9
// 512.222 us; speedup vs baseline: 1.0628x; 1.0301x over previous
//
#include <hip/hip_runtime.h>
#include <cstdint>
#include <cstddef>

#define BB 128
#define TT 512
#define DD 100
#define HH 100
#define NG 400   // 4*H
#define LL 25
#define F_LOG2E 1.44269504088896340736f
#define F_LN2   0.69314718055994530942f

typedef __decltype(__builtin_amdgcn_cvt_pkrtz(0.f, 0.f)) h2_t;
typedef _Float16 v8h __attribute__((ext_vector_type(8)));
typedef float v4f __attribute__((ext_vector_type(4)));

__device__ __forceinline__ h2_t bc_h2(unsigned int u) {
  return __builtin_bit_cast(h2_t, u);
}
__device__ __forceinline__ unsigned int pk(float x, float y) {
  return __builtin_bit_cast(unsigned int, __builtin_amdgcn_cvt_pkrtz(x, y));
}

__device__ __forceinline__ float fdot2(h2_t a, h2_t b, float c) {
#if __has_builtin(__builtin_amdgcn_fdot2)
  return __builtin_amdgcn_fdot2(a, b, c, false);
#else
  return c + (float)a[0] * (float)b[0] + (float)a[1] * (float)b[1];
#endif
}

__device__ __forceinline__ float fexp2(float x) { return __builtin_amdgcn_exp2f(x); }
__device__ __forceinline__ float flog2(float x) { return __builtin_amdgcn_logf(x); }
__device__ __forceinline__ float frcp(float x)  { return __builtin_amdgcn_rcpf(x); }

__device__ __forceinline__ float sigmoid_f(float x) {
  return frcp(1.f + fexp2(-F_LOG2E * x));
}
__device__ __forceinline__ float tanh_f(float x) {
  float e = fexp2(2.f * F_LOG2E * x);
  return 1.f - 2.f * frcp(e + 1.f);
}

// quad all-reduce add via DPP. xor1 = quad_perm[1,0,3,2] = 177; xor2 = 78.
template <int CTRL>
__device__ __forceinline__ float qadd(float v) {
#if __has_builtin(__builtin_amdgcn_mov_dpp)
  int m = __builtin_amdgcn_mov_dpp(__builtin_bit_cast(int, v), CTRL, 0xF, 0xF, true);
  return v + __builtin_bit_cast(float, m);
#else
  int x = (CTRL == 177) ? 1 : 2;
  return v + __shfl_xor(v, x);
#endif
}

// quad broadcast of lane LANE (0..3) via DPP quad_perm[L,L,L,L].
template <int LANE>
__device__ __forceinline__ float qbcast(float v) {
#if __has_builtin(__builtin_amdgcn_mov_dpp)
  int m = __builtin_amdgcn_mov_dpp(__builtin_bit_cast(int, v), LANE * 0x55, 0xF, 0xF, true);
  return __builtin_bit_cast(float, m);
#else
  return __shfl(v, (threadIdx.x & 63 & ~3) + LANE);
#endif
}

__device__ __forceinline__ float bperm(float v, int byteidx) {
  return __builtin_bit_cast(float,
      __builtin_amdgcn_ds_bpermute(byteidx, __builtin_bit_cast(int, v)));
}
__device__ __forceinline__ float rfl(float v) {
  return __builtin_bit_cast(float,
      __builtin_amdgcn_readfirstlane(__builtin_bit_cast(int, v)));
}

// LDS-visibility-only barrier (vmcnt left free): imm 0xC07F.
__device__ __forceinline__ void lds_barrier() {
  __builtin_amdgcn_s_waitcnt(0xC07F);
  __builtin_amdgcn_s_barrier();
}

// ---------------------------------------------------------------------------
// FUSED BiLSTM scan + x-side GEMM + emissions. One block per (batch, dir),
// 512 threads = 8 waves, 1 block/CU (100 KB LDS). 4 tiles of 128 steps:
//   BURST: all 8 waves compute gin tile via mfma_f32_16x16x32_f16 (wave w =
//   rows 16w..16w+15 in scan order; verified gin_mfma2 fragment mapping;
//   store permutation p(n)=4*(n%100)+n/100 into gin_lds as f16, no bias).
//   SCAN (v6 structure): unit lane (j=tid>>2, gate s=tid&3) reads its gin
//   value from gin_lds via depth-1 LDS prefetch, +bias (moved here), 4x14
//   fdot2 on h, DPP quad reduce/bcast, redundant c update. Wave 7 = 50
//   emission lanes, one step behind. No gin global round-trip at all.
// ---------------------------------------------------------------------------
__global__ __launch_bounds__(512, 2) void lstm_fused(
    const int* __restrict__ tok, const float* __restrict__ emb,
    const float* __restrict__ w_ih_f, const float* __restrict__ w_ih_b,
    const float* __restrict__ b_ih_f, const float* __restrict__ b_hh_f,
    const float* __restrict__ b_ih_b, const float* __restrict__ b_hh_b,
    const float* __restrict__ w_hh_f, const float* __restrict__ w_hh_b,
    const float* __restrict__ w_tag, const float* __restrict__ b_tag,
    float* __restrict__ em_f, float* __restrict__ em_b)
{
  const int tid = threadIdx.x;
  const int b   = blockIdx.x & 127;
  const int dir = blockIdx.x >> 7;
  const float* w_hh = dir ? w_hh_b : w_hh_f;
  const float* w_ih = dir ? w_ih_b : w_ih_f;
  const float* b_ih = dir ? b_ih_b : b_ih_f;
  const float* b_hh = dir ? b_hh_b : b_hh_f;

  __shared__ __align__(16) unsigned short gin_lds[128 * 400];  // 100 KB
  __shared__ __align__(16) unsigned int hls0[52];
  __shared__ __align__(16) unsigned int hls1[52];

  // ---- scan state (v6) ----
  const bool uact = tid < NG;
  const int j = tid >> 2;
  const int s = tid & 3;
  const int od = 12 * s;
  const int nn = (s == 3) ? 14 : 12;

  h2_t wA[14], wB[14], wC[14], wD[14];
  float bias = 0.f;
  if (uact) {
#pragma unroll
    for (int d = 0; d < 14; ++d) {
      int dd = (d < nn) ? (od + d) : 0;
      const float* r0 = w_hh + (size_t)(0 * 100 + j) * HH + 2 * dd;
      const float* r1 = w_hh + (size_t)(1 * 100 + j) * HH + 2 * dd;
      const float* r2 = w_hh + (size_t)(2 * 100 + j) * HH + 2 * dd;
      const float* r3 = w_hh + (size_t)(3 * 100 + j) * HH + 2 * dd;
      h2_t z = __builtin_amdgcn_cvt_pkrtz(0.f, 0.f);
      wA[d] = (d < nn) ? __builtin_amdgcn_cvt_pkrtz(r0[0], r0[1]) : z;
      wB[d] = (d < nn) ? __builtin_amdgcn_cvt_pkrtz(r1[0], r1[1]) : z;
      wC[d] = (d < nn) ? __builtin_amdgcn_cvt_pkrtz(r2[0], r2[1]) : z;
      wD[d] = (d < nn) ? __builtin_amdgcn_cvt_pkrtz(r3[0], r3[1]) : z;
    }
    bias = b_ih[s * 100 + j] + b_hh[s * 100 + j];
  }
  const float kk2 = (s == 2) ? (2.f * F_LOG2E) : (-F_LOG2E);
  const float cA  = (s == 2) ? -2.f : 1.f;
  const float cB  = (s == 2) ? 1.f : 0.f;

  // emission lanes: wave 7
  const int el = tid - 448;
  const bool eact = (el >= 0) && (el < 50);
  const int l  = (el >= 0) ? (el >> 1) : 0;
  const int hf = (el >= 0) ? (el & 1) : 0;
  const int eo = hf ? 24 : 0;
  const int en = hf ? 26 : 24;
  h2_t wt[26];
  float bt = 0.f;
  if (eact) {
    const float* wr = w_tag + (size_t)l * 200 + dir * 100;
#pragma unroll
    for (int d = 0; d < 26; ++d) {
      int dd = (d < en) ? (eo + d) : 0;
      h2_t z = __builtin_amdgcn_cvt_pkrtz(0.f, 0.f);
      wt[d] = (d < en) ? __builtin_amdgcn_cvt_pkrtz(wr[2 * dd], wr[2 * dd + 1]) : z;
    }
    if (dir == 0 && hf == 0) bt = b_tag[l];
  }
  float* emo = dir ? em_b : em_f;
  float* emp = emo + ((size_t)b * TT + (dir ? (TT - 1) : 0)) * LL + l;
  const ptrdiff_t estep = dir ? -(ptrdiff_t)LL : (ptrdiff_t)LL;

  if (tid < 52) { hls0[tid] = 0u; hls1[tid] = 0u; }

  // burst lane mapping
  const int wv   = tid >> 6;
  const int lane = tid & 63;
  const int l16  = lane & 15;
  const int quad = lane >> 4;

  float c = 0.f;
  unsigned short gnext = 0;
  int grow = 0;

#define SDOT(d, hh) \
  p0 = fdot2(wA[d], bc_h2(hh), p0); p1 = fdot2(wB[d], bc_h2(hh), p1); \
  p2 = fdot2(wC[d], bc_h2(hh), p2); p3 = fdot2(wD[d], bc_h2(hh), p3);
#define EDOT(d, hh) { h2_t h = bc_h2(hh); \
  if ((d & 3) == 0) a0 = fdot2(wt[d], h, a0); \
  else if ((d & 3) == 1) a1 = fdot2(wt[d], h, a1); \
  else if ((d & 3) == 2) a2 = fdot2(wt[d], h, a2); \
  else a3 = fdot2(wt[d], h, a3); }

#define SCAN_STEP(HRD, HWR, TVNZ)                                          \
  {                                                                        \
    if (uact) {                                                            \
      unsigned short gcurr = gnext;                                        \
      int nr = (grow < 127) ? grow + 1 : 127;                              \
      gnext = gin_lds[nr * 400 + tid];                                     \
      grow = nr;                                                           \
      const unsigned int* hp = (HRD) + od;                                 \
      uint4 u0 = *((const uint4*)hp);                                      \
      uint4 u1 = *((const uint4*)(hp + 4));                                \
      uint4 u2 = *((const uint4*)(hp + 8));                                \
      uint2 u3 = *((const uint2*)(hp + 12));                               \
      float p0, p1, p2, p3;                                                \
      p0 = fdot2(wA[0], bc_h2(u0.x), 0.f);                                 \
      p1 = fdot2(wB[0], bc_h2(u0.x), 0.f);                                 \
      p2 = fdot2(wC[0], bc_h2(u0.x), 0.f);                                 \
      p3 = fdot2(wD[0], bc_h2(u0.x), 0.f);                                 \
      SDOT(1, u0.y)  SDOT(2, u0.z)  SDOT(3, u0.w)                          \
      SDOT(4, u1.x)  SDOT(5, u1.y)  SDOT(6, u1.z)  SDOT(7, u1.w)           \
      SDOT(8, u2.x)  SDOT(9, u2.y)  SDOT(10, u2.z) SDOT(11, u2.w)          \
      SDOT(12, u3.x) SDOT(13, u3.y)                                        \
      p0 = qadd<78>(qadd<177>(p0));                                        \
      p1 = qadd<78>(qadd<177>(p1));                                        \
      p2 = qadd<78>(qadd<177>(p2));                                        \
      p3 = qadd<78>(qadd<177>(p3));                                        \
      float psel = (s == 0) ? p0 : (s == 1) ? p1 : (s == 2) ? p2 : p3;     \
      float gate = psel + bias + (float)__builtin_bit_cast(__fp16, gcurr); \
      float y  = fexp2(kk2 * gate);                                        \
      float rr = frcp(1.f + y);                                            \
      float actv = fmaf(cA, rr, cB);                                       \
      float iv = qbcast<0>(actv);                                          \
      float fv = qbcast<1>(actv);                                          \
      float gv = qbcast<2>(actv);                                          \
      float ov = qbcast<3>(actv);                                          \
      c = fmaf(fv, c, iv * gv);                                            \
      float hvv = ov * tanh_f(c);                                          \
      if (s == 0) ((__fp16*)(HWR))[j] = (__fp16)hvv;                       \
    } else if (eact && (TVNZ)) {                                           \
      const unsigned int* hp = (HRD) + eo;                                 \
      uint4 e0 = *((const uint4*)hp);                                      \
      uint4 e1 = *((const uint4*)(hp + 4));                                \
      uint4 e2 = *((const uint4*)(hp + 8));                                \
      uint4 e3 = *((const uint4*)(hp + 12));                               \
      uint4 e4 = *((const uint4*)(hp + 16));                               \
      uint4 e5 = *((const uint4*)(hp + 20));                               \
      uint2 e6 = *((const uint2*)(hp + 24));                               \
      float a0, a1, a2, a3;                                                \
      a0 = fdot2(wt[0], bc_h2(e0.x), 0.f);                                 \
      a1 = fdot2(wt[1], bc_h2(e0.y), 0.f);                                 \
      a2 = fdot2(wt[2], bc_h2(e0.z), 0.f);                                 \
      a3 = fdot2(wt[3], bc_h2(e0.w), 0.f);                                 \
      EDOT(4, e1.x)  EDOT(5, e1.y)  EDOT(6, e1.z)  EDOT(7, e1.w)           \
      EDOT(8, e2.x)  EDOT(9, e2.y)  EDOT(10, e2.z) EDOT(11, e2.w)          \
      EDOT(12, e3.x) EDOT(13, e3.y) EDOT(14, e3.z) EDOT(15, e3.w)          \
      EDOT(16, e4.x) EDOT(17, e4.y) EDOT(18, e4.z) EDOT(19, e4.w)          \
      EDOT(20, e5.x) EDOT(21, e5.y) EDOT(22, e5.z) EDOT(23, e5.w)          \
      EDOT(24, e6.x) EDOT(25, e6.y)                                        \
      float ss = (a0 + a1) + (a2 + a3);                                    \
      float tot = qadd<177>(ss);                                           \
      if (hf == 0) *emp = tot + bt;                                        \
      emp += estep;                                                        \
    }                                                                      \
    lds_barrier();                                                         \
  }

  for (int T = 0; T < 4; ++T) {
    // ---- BURST: fill gin_lds for scan steps T*128 .. T*128+127 ----
    {
      const int ii = T * 128 + wv * 16 + l16;     // scan-order step index
      const int tt = dir ? (TT - 1 - ii) : ii;
      const int tk = tok[b * TT + tt];
      const float* xr = emb + (size_t)tk * DD;
      const int kb = quad * 8;
      v8h af[4];
#pragma unroll
      for (int f = 0; f < 4; ++f) {
        uint4 u;
        if (f < 3) {
          const float* xp = xr + f * 32 + kb;
          float4 va = *(const float4*)(xp);
          float4 vb = *(const float4*)(xp + 4);
          u.x = pk(va.x, va.y); u.y = pk(va.z, va.w);
          u.z = pk(vb.x, vb.y); u.w = pk(vb.z, vb.w);
        } else {
          // A may hold garbage for k>=100: B side is zero there.
          float4 va = *(const float4*)(xr + 96);
          u.x = pk(va.x, va.y); u.y = pk(va.z, va.w);
          u.z = 0u; u.w = 0u;
        }
        af[f] = __builtin_bit_cast(v8h, u);
      }
      __fp16* gout = (__fp16*)gin_lds;
      const int rowb = wv * 16 + quad * 4;
      for (int cc = 0; cc < 25; ++cc) {
        const int n = 16 * cc + l16;              // natural gate row
        const float* wr = w_ih + (size_t)n * DD;
        v8h bf[4];
#pragma unroll
        for (int f = 0; f < 3; ++f) {
          const float* wp = wr + f * 32 + quad * 8;
          float4 va = *(const float4*)(wp);
          float4 vb = *(const float4*)(wp + 4);
          uint4 u;
          u.x = pk(va.x, va.y); u.y = pk(va.z, va.w);
          u.z = pk(vb.x, vb.y); u.w = pk(vb.z, vb.w);
          bf[f] = __builtin_bit_cast(v8h, u);
        }
        {
          uint4 u = {0u, 0u, 0u, 0u};
          if (quad == 0) {
            float4 va = *(const float4*)(wr + 96);
            u.x = pk(va.x, va.y); u.y = pk(va.z, va.w);
          }
          bf[3] = __builtin_bit_cast(v8h, u);
        }
        v4f acc = {0.f, 0.f, 0.f, 0.f};
#pragma unroll
        for (int f = 0; f < 4; ++f)
          acc = __builtin_amdgcn_mfma_f32_16x16x32_f16(af[f], bf[f], acc, 0, 0, 0);
        // store permutation p(n) = 4*(n%100) + n/100
        const int qn = (n * 41) >> 12;
        const int p  = ((n - 100 * qn) << 2) + qn;
#pragma unroll
        for (int r = 0; r < 4; ++r)
          gout[(rowb + r) * 400 + p] = (__fp16)acc[r];
      }
    }
    __syncthreads();
    if (uact) { grow = 0; gnext = gin_lds[tid]; }

    // ---- 128 scan steps (64 unrolled pairs) ----
    SCAN_STEP(hls0, hls1, (T > 0))
    SCAN_STEP(hls1, hls0, true)
    for (int it = 1; it < 64; ++it) {
      SCAN_STEP(hls0, hls1, true)
      SCAN_STEP(hls1, hls0, true)
    }
  }
#undef SCAN_STEP
#undef SDOT

  // epilogue: emission for the last h (in hls0)
  if (eact) {
    const unsigned int* hp = hls0 + eo;
    uint4 e0 = *((const uint4*)hp);
    uint4 e1 = *((const uint4*)(hp + 4));
    uint4 e2 = *((const uint4*)(hp + 8));
    uint4 e3 = *((const uint4*)(hp + 12));
    uint4 e4 = *((const uint4*)(hp + 16));
    uint4 e5 = *((const uint4*)(hp + 20));
    uint2 e6 = *((const uint2*)(hp + 24));
    float a0, a1, a2, a3;
    a0 = fdot2(wt[0], bc_h2(e0.x), 0.f);
    a1 = fdot2(wt[1], bc_h2(e0.y), 0.f);
    a2 = fdot2(wt[2], bc_h2(e0.z), 0.f);
    a3 = fdot2(wt[3], bc_h2(e0.w), 0.f);
    EDOT(4, e1.x)  EDOT(5, e1.y)  EDOT(6, e1.z)  EDOT(7, e1.w)
    EDOT(8, e2.x)  EDOT(9, e2.y)  EDOT(10, e2.z) EDOT(11, e2.w)
    EDOT(12, e3.x) EDOT(13, e3.y) EDOT(14, e3.z) EDOT(15, e3.w)
    EDOT(16, e4.x) EDOT(17, e4.y) EDOT(18, e4.z) EDOT(19, e4.w)
    EDOT(20, e5.x) EDOT(21, e5.y) EDOT(22, e5.z) EDOT(23, e5.w)
    EDOT(24, e6.x) EDOT(25, e6.y)
    float ss = (a0 + a1) + (a2 + a3);
    float tot = qadd<177>(ss);
    if (hf == 0) {
      int ttp = dir ? 0 : (TT - 1);
      emo[((size_t)b * TT + ttp) * LL + l] = tot + bt;
    }
  }
#undef EDOT
}

// ---------------------------------------------------------------------------
// FALLBACK scan (small ws): writes hc16 f16.
// ---------------------------------------------------------------------------
__global__ __launch_bounds__(512, 2) void lstm_scan_fb(
    const int* __restrict__ tok, const float* __restrict__ emb,
    const float* __restrict__ w_ih_f, const float* __restrict__ w_hh_f,
    const float* __restrict__ b_ih_f, const float* __restrict__ b_hh_f,
    const float* __restrict__ w_ih_b, const float* __restrict__ w_hh_b,
    const float* __restrict__ b_ih_b, const float* __restrict__ b_hh_b,
    unsigned short* __restrict__ hc16)
{
  const int tid = threadIdx.x;
  const int b   = blockIdx.x & 127;
  const int dir = blockIdx.x >> 7;

  const float* w_ih = dir ? w_ih_b : w_ih_f;
  const float* w_hh = dir ? w_hh_b : w_hh_f;
  const float* b_ih = dir ? b_ih_b : b_ih_f;
  const float* b_hh = dir ? b_hh_b : b_hh_f;

  __shared__ __align__(16) unsigned int xs[2][64];
  __shared__ __align__(16) unsigned int hls[64];
  __shared__ float gl[NG];

  h2_t wih[50], whh[50];
  float bias = 0.f;
  if (tid < NG) {
    const float4* wi = (const float4*)(w_ih + tid * DD);
    const float4* wh = (const float4*)(w_hh + tid * DD);
#pragma unroll
    for (int kk = 0; kk < 25; ++kk) {
      float4 a = wi[kk];
      wih[2 * kk]     = __builtin_amdgcn_cvt_pkrtz(a.x, a.y);
      wih[2 * kk + 1] = __builtin_amdgcn_cvt_pkrtz(a.z, a.w);
      float4 c = wh[kk];
      whh[2 * kk]     = __builtin_amdgcn_cvt_pkrtz(c.x, c.y);
      whh[2 * kk + 1] = __builtin_amdgcn_cvt_pkrtz(c.z, c.w);
    }
    bias = b_ih[tid] + b_hh[tid];
  }
  if (tid < 2) { xs[0][50 + tid] = 0u; xs[1][50 + tid] = 0u; hls[50 + tid] = 0u; }
  if (tid < 50) hls[tid] = 0u;

  const int base = b * TT;
  if (tid >= 448 && tid < 498) {
    int tt0 = dir ? (TT - 1) : 0;
    int i = tid - 448;
    int tk = tok[base + tt0];
    float2 v = ((const float2*)(emb + (size_t)tk * DD))[i];
    xs[0][i] = pk(v.x, v.y);
  }
  __syncthreads();

  float cst = 0.f;
  unsigned short* hcb = hc16 + (size_t)base * 200 + dir * 100;

  for (int t = 0; t < TT; ++t) {
    const int buf = t & 1;
    const int tt  = dir ? (TT - 1 - t) : t;

    if (tid < NG) {
      float a0 = bias, a1 = 0.f, a2 = 0.f, a3 = 0.f;
      const unsigned int* xp = xs[buf];
#pragma unroll
      for (int g = 0; g < 13; ++g) {
        uint4 u = ((const uint4*)xp)[g];
        const int k = 4 * g;
        a0 = fdot2(wih[k], bc_h2(u.x), a0);
        a1 = fdot2(wih[k + 1], bc_h2(u.y), a1);
        if (k + 2 < 50) a2 = fdot2(wih[k + 2], bc_h2(u.z), a2);
        if (k + 3 < 50) a3 = fdot2(wih[k + 3], bc_h2(u.w), a3);
      }
#pragma unroll
      for (int g = 0; g < 13; ++g) {
        uint4 u = ((const uint4*)hls)[g];
        const int k = 4 * g;
        a0 = fdot2(whh[k], bc_h2(u.x), a0);
        a1 = fdot2(whh[k + 1], bc_h2(u.y), a1);
        if (k + 2 < 50) a2 = fdot2(whh[k + 2], bc_h2(u.z), a2);
        if (k + 3 < 50) a3 = fdot2(whh[k + 3], bc_h2(u.w), a3);
      }
      float accs = (a0 + a1) + (a2 + a3);
      float av = (tid >= 200 && tid < 300) ? tanh_f(accs) : sigmoid_f(accs);
      gl[tid] = av;
    } else if (tid >= 448 && tid < 498 && t < TT - 1) {
      int ttn = dir ? (TT - 2 - t) : (t + 1);
      int i = tid - 448;
      int tk = tok[base + ttn];
      float2 v = ((const float2*)(emb + (size_t)tk * DD))[i];
      xs[buf ^ 1][i] = pk(v.x, v.y);
    }
    __syncthreads();

    if (tid < HH) {
      float gi = gl[tid], gf = gl[tid + 100], gg = gl[tid + 200], go = gl[tid + 300];
      cst = gf * cst + gi * gg;
      float hv = go * tanh_f(cst);
      __fp16 h16 = (__fp16)hv;
      ((__fp16*)hls)[tid] = h16;
      hcb[(size_t)tt * 200 + tid] = __builtin_bit_cast(unsigned short, h16);
    }
    __syncthreads();
  }
}

// Fallback emissions kernel.
__global__ __launch_bounds__(256, 2) void emis2(
    const unsigned short* __restrict__ hc16, const float* __restrict__ w_tag,
    const float* __restrict__ b_tag, float* __restrict__ em)
{
  __shared__ unsigned int hsh[64 * 101];
  __shared__ unsigned int wsh[25 * 100];
  const int tid = threadIdx.x;
  const size_t m0 = (size_t)blockIdx.x * 64;

  const unsigned int* hcu = (const unsigned int*)hc16;
  for (int i = tid; i < 64 * 100; i += 256) {
    int r = i / 100;
    int k = i - r * 100;
    hsh[r * 101 + k] = hcu[m0 * 100 + i];
  }
  for (int i = tid; i < 25 * 100; i += 256) {
    float2 wv = ((const float2*)w_tag)[i];
    wsh[i] = pk(wv.x, wv.y);
  }
  __syncthreads();

  const int r = tid & 63, q = tid >> 6;
  int lidx[7];
  bool lv[7];
  float acc[7];
#pragma unroll
  for (int ii = 0; ii < 7; ++ii) {
    int l = q + 4 * ii;
    lv[ii] = (l < LL);
    lidx[ii] = lv[ii] ? l : 0;
    acc[ii] = lv[ii] ? b_tag[lidx[ii]] : 0.f;
  }
  const unsigned int* hrow = hsh + r * 101;
#pragma unroll 2
  for (int k = 0; k < 100; ++k) {
    h2_t hv = bc_h2(hrow[k]);
#pragma unroll
    for (int ii = 0; ii < 7; ++ii)
      acc[ii] = fdot2(hv, bc_h2(wsh[lidx[ii] * 100 + k]), acc[ii]);
  }
#pragma unroll
  for (int ii = 0; ii < 7; ++ii)
    if (lv[ii]) em[(m0 + r) * LL + lidx[ii]] = acc[ii];
}

// ---------------------------------------------------------------------------
// CRF: matvec scan, ONE exp per lane per step, depth-2 em prefetch.
// ---------------------------------------------------------------------------
__global__ __launch_bounds__(128) void crf_scan5(
    const float* __restrict__ em_f, const float* __restrict__ em_b,
    const int* __restrict__ tags, const int* __restrict__ lengths,
    const float* __restrict__ trans,
    const float* __restrict__ startt, const float* __restrict__ endt,
    float* __restrict__ ab, float* __restrict__ gold)
{
  const int tid  = threadIdx.x;
  const int b    = blockIdx.x >> 1;
  const int side = blockIdx.x & 1;

  if (tid < 64) {
    const int lane = tid;
    const int j = (lane < LL) ? lane : 0;
    const float* ef = em_f + (size_t)b * TT * LL;
    const float* eb = em_b + (size_t)b * TT * LL;

    float E[LL];
#pragma unroll
    for (int i = 0; i < LL; ++i) {
      float tv = (side == 0 ? trans[i * LL + j] : trans[j * LL + i]);
      E[i] = fexp2(tv * F_LOG2E);
    }

    float a, C = 0.f;
    if (side == 0) {
      a = (startt[j] + ef[j] + eb[j]) * F_LOG2E;
      float efA = ef[LL + j],     ebA = eb[LL + j];
      float efB = ef[2 * LL + j], ebB = eb[2 * LL + j];
      for (int t = 1; t < 256; ++t) {
        float em2 = (efA + ebA) * F_LOG2E;
        int tn = (t + 2 < 256) ? (t + 2) : 255;
        efA = efB; ebA = ebB;
        efB = ef[(size_t)tn * LL + j];
        ebB = eb[(size_t)tn * LL + j];
        float sh = rfl(a);
        C += sh;
        float A = fexp2(a - sh);
        float s0 = 0.f, s1 = 0.f, s2 = 0.f, s3 = 0.f;
#pragma unroll
        for (int i = 0; i < LL; ++i) {
          float Ai = bperm(A, 4 * i);
          if ((i & 3) == 0) s0 = fmaf(Ai, E[i], s0);
          else if ((i & 3) == 1) s1 = fmaf(Ai, E[i], s1);
          else if ((i & 3) == 2) s2 = fmaf(Ai, E[i], s2);
          else s3 = fmaf(Ai, E[i], s3);
        }
        a = flog2((s0 + s1) + (s2 + s3)) + em2;
      }
    } else {
      a = endt[j] * F_LOG2E;
      float efA = ef[(size_t)(TT - 1) * LL + j], ebA = eb[(size_t)(TT - 1) * LL + j];
      float efB = ef[(size_t)(TT - 2) * LL + j], ebB = eb[(size_t)(TT - 2) * LL + j];
      for (int stpi = 0; stpi < 256; ++stpi) {
        float em2 = (efA + ebA) * F_LOG2E;
        int t1n = (stpi + 2 < 256) ? (TT - 3 - stpi) : 256;
        efA = efB; ebA = ebB;
        efB = ef[(size_t)t1n * LL + j];
        ebB = eb[(size_t)t1n * LL + j];
        float v = a + em2;
        float sh = rfl(v);
        C += sh;
        float A = fexp2(v - sh);
        float s0 = 0.f, s1 = 0.f, s2 = 0.f, s3 = 0.f;
#pragma unroll
        for (int i = 0; i < LL; ++i) {
          float Ai = bperm(A, 4 * i);
          if ((i & 3) == 0) s0 = fmaf(Ai, E[i], s0);
          else if ((i & 3) == 1) s1 = fmaf(Ai, E[i], s1);
          else if ((i & 3) == 2) s2 = fmaf(Ai, E[i], s2);
          else s3 = fmaf(Ai, E[i], s3);
        }
        a = flog2((s0 + s1) + (s2 + s3));
      }
    }
    if (lane < LL)
      ab[((size_t)b * 2 + side) * LL + lane] = (a + C) * F_LN2;
  } else if (side == 0) {
    const int lane = tid - 64;
    const int len = lengths[b];
    float acc = 0.f;
#pragma unroll
    for (int k = 0; k < 8; ++k) {
      int t = k * 64 + lane;
      int tg = tags[b * TT + t];
      size_t ei = ((size_t)b * TT + t) * LL + tg;
      float e = em_f[ei] + em_b[ei];
      float term;
      if (t == 0) term = startt[tg] + e;
      else        term = trans[tags[b * TT + t - 1] * LL + tg] + e;
      if (t == len - 1) term += endt[tg];
      if (t < len) acc += term;
    }
    for (int o = 32; o > 0; o >>= 1) acc += __shfl_down(acc, o);
    if (lane == 0) gold[b] = acc;
  }
}

// ---------------------------------------------------------------------------
// Final: logZ_b = lse(alpha+beta), out = sum_b (logZ_b - gold_b)
// ---------------------------------------------------------------------------
__global__ __launch_bounds__(128, 4) void crf_final(
    const float* __restrict__ ab, const float* __restrict__ gold,
    float* __restrict__ out)
{
  const int b = threadIdx.x;
  float v[LL];
  float m = -1e30f;
#pragma unroll
  for (int l = 0; l < LL; ++l) {
    v[l] = ab[((size_t)b * 2) * LL + l] + ab[((size_t)b * 2 + 1) * LL + l];
    m = fmaxf(m, v[l]);
  }
  float sacc = 0.f;
#pragma unroll
  for (int l = 0; l < LL; ++l) sacc += fexp2((v[l] - m) * F_LOG2E);
  float nll = (m + flog2(sacc) * F_LN2) - gold[b];

  for (int o = 32; o > 0; o >>= 1) nll += __shfl_down(nll, o);
  __shared__ float r2[2];
  if ((b & 63) == 0) r2[b >> 6] = nll;
  __syncthreads();
  if (b == 0) out[0] = r2[0] + r2[1];
}

extern "C" void kernel_launch(void* const* d_in, const int* in_sizes, int n_in,
                              void* d_out, int out_size, void* d_ws, size_t ws_size,
                              hipStream_t stream) {
  const int*   tok   = (const int*)d_in[0];
  const int*   tags  = (const int*)d_in[1];
  const int*   lens  = (const int*)d_in[2];
  const float* emb   = (const float*)d_in[3];
  const float* wif   = (const float*)d_in[4];
  const float* whf   = (const float*)d_in[5];
  const float* bif   = (const float*)d_in[6];
  const float* bhf   = (const float*)d_in[7];
  const float* wib   = (const float*)d_in[8];
  const float* whb   = (const float*)d_in[9];
  const float* bib   = (const float*)d_in[10];
  const float* bhb   = (const float*)d_in[11];
  const float* wtag  = (const float*)d_in[12];
  const float* btag  = (const float*)d_in[13];
  const float* trans = (const float*)d_in[14];
  const float* st    = (const float*)d_in[15];
  const float* en    = (const float*)d_in[16];

  char* wsb = (char*)d_ws;
  float* em_f = (float*)wsb;                                   //  6,553,600 B
  float* em_b = (float*)(wsb + 6553600);                       //  6,553,600 B
  float* gold = (float*)(wsb + 13107200);                      //        512 B
  float* ab   = (float*)(wsb + 13107712);                      //     25,600 B
  const size_t need_fused = 13133312ULL;
  const size_t need_fb    = 13133312ULL + 26214400ULL;

  if (ws_size >= need_fused) {
    lstm_fused<<<256, 512, 0, stream>>>(tok, emb, wif, wib, bif, bhf, bib, bhb,
                                        whf, whb, wtag, btag, em_f, em_b);
  } else if (ws_size >= need_fb) {
    unsigned short* hc16 = (unsigned short*)(wsb + 13133312);
    hipMemsetAsync(em_b, 0, 6553600, stream);
    lstm_scan_fb<<<256, 512, 0, stream>>>(tok, emb, wif, whf, bif, bhf,
                                          wib, whb, bib, bhb, hc16);
    emis2<<<1024, 256, 0, stream>>>(hc16, wtag, btag, em_f);
  }
  crf_scan5<<<256, 128, 0, stream>>>(em_f, em_b, tags, lens, trans, st, en, ab, gold);
  crf_final<<<1, 128, 0, stream>>>(ab, gold, (float*)d_out);
}

// Round 10
// 433.106 us; speedup vs baseline: 1.2569x; 1.1827x over previous
//
#include <hip/hip_runtime.h>
#include <cstdint>
#include <cstddef>

#define BB 128
#define TT 512
#define DD 100
#define HH 100
#define NG 400   // 4*H
#define LL 25
#define TS 32    // scan tile (steps per burst)
#define NTILE 16
#define F_LOG2E 1.44269504088896340736f
#define F_LN2   0.69314718055994530942f

typedef __decltype(__builtin_amdgcn_cvt_pkrtz(0.f, 0.f)) h2_t;
typedef _Float16 v8h __attribute__((ext_vector_type(8)));
typedef float v4f __attribute__((ext_vector_type(4)));

__device__ __forceinline__ h2_t bc_h2(unsigned int u) {
  return __builtin_bit_cast(h2_t, u);
}
__device__ __forceinline__ unsigned int pk(float x, float y) {
  return __builtin_bit_cast(unsigned int, __builtin_amdgcn_cvt_pkrtz(x, y));
}

__device__ __forceinline__ float fdot2(h2_t a, h2_t b, float c) {
#if __has_builtin(__builtin_amdgcn_fdot2)
  return __builtin_amdgcn_fdot2(a, b, c, false);
#else
  return c + (float)a[0] * (float)b[0] + (float)a[1] * (float)b[1];
#endif
}

__device__ __forceinline__ float fexp2(float x) { return __builtin_amdgcn_exp2f(x); }
__device__ __forceinline__ float flog2(float x) { return __builtin_amdgcn_logf(x); }
__device__ __forceinline__ float frcp(float x)  { return __builtin_amdgcn_rcpf(x); }

__device__ __forceinline__ float sigmoid_f(float x) {
  return frcp(1.f + fexp2(-F_LOG2E * x));
}
__device__ __forceinline__ float tanh_f(float x) {
  float e = fexp2(2.f * F_LOG2E * x);
  return 1.f - 2.f * frcp(e + 1.f);
}

template <int CTRL>
__device__ __forceinline__ float qadd(float v) {
#if __has_builtin(__builtin_amdgcn_mov_dpp)
  int m = __builtin_amdgcn_mov_dpp(__builtin_bit_cast(int, v), CTRL, 0xF, 0xF, true);
  return v + __builtin_bit_cast(float, m);
#else
  int x = (CTRL == 177) ? 1 : 2;
  return v + __shfl_xor(v, x);
#endif
}

template <int LANE>
__device__ __forceinline__ float qbcast(float v) {
#if __has_builtin(__builtin_amdgcn_mov_dpp)
  int m = __builtin_amdgcn_mov_dpp(__builtin_bit_cast(int, v), LANE * 0x55, 0xF, 0xF, true);
  return __builtin_bit_cast(float, m);
#else
  return __shfl(v, (threadIdx.x & 63 & ~3) + LANE);
#endif
}

__device__ __forceinline__ float bperm(float v, int byteidx) {
  return __builtin_bit_cast(float,
      __builtin_amdgcn_ds_bpermute(byteidx, __builtin_bit_cast(int, v)));
}
__device__ __forceinline__ float rfl(float v) {
  return __builtin_bit_cast(float,
      __builtin_amdgcn_readfirstlane(__builtin_bit_cast(int, v)));
}

// LDS-visibility-only barrier (vmcnt left free): imm 0xC07F.
__device__ __forceinline__ void lds_barrier() {
  __builtin_amdgcn_s_waitcnt(0xC07F);
  __builtin_amdgcn_s_barrier();
}

// ---------------------------------------------------------------------------
// FUSED BiLSTM + x-GEMM + emissions, v2. One block per (batch, dir), 512 thr.
// w_ih staged to LDS ONCE (f16, K-padded 128, stride 68 dw, pad zeroed);
// x tiles (32 steps) register-prefetched one tile early, written at boundary.
// BURST (per tile): wave w owns c in [25w/8, 25(w+1)/8) columns x 2 m-tiles;
// A/B frags from LDS, 4x mfma_16x16x32_f16, store perm p(n)=4*(n%100)+n/100
// into gin_lds. SCAN: v6 structure (depth-1 gin LDS prefetch, DPP quad ops).
// ---------------------------------------------------------------------------
__global__ __launch_bounds__(512, 2) void lstm_fused2(
    const int* __restrict__ tok, const float* __restrict__ emb,
    const float* __restrict__ w_ih_f, const float* __restrict__ w_ih_b,
    const float* __restrict__ b_ih_f, const float* __restrict__ b_hh_f,
    const float* __restrict__ b_ih_b, const float* __restrict__ b_hh_b,
    const float* __restrict__ w_hh_f, const float* __restrict__ w_hh_b,
    const float* __restrict__ w_tag, const float* __restrict__ b_tag,
    float* __restrict__ em_f, float* __restrict__ em_b)
{
  const int tid = threadIdx.x;
  const int b   = blockIdx.x & 127;
  const int dir = blockIdx.x >> 7;
  const float* w_hh = dir ? w_hh_b : w_hh_f;
  const float* w_ih = dir ? w_ih_b : w_ih_f;
  const float* b_ih = dir ? b_ih_b : b_ih_f;
  const float* b_hh = dir ? b_hh_b : b_hh_f;

  __shared__ __align__(16) unsigned int wlds[400 * 68];        // 108.8 KB
  __shared__ __align__(16) unsigned short gin_lds[TS * 400];   // 25.6 KB
  __shared__ __align__(16) unsigned int xlds[TS * 68];         // 8.7 KB
  __shared__ __align__(16) unsigned int hls0[52];
  __shared__ __align__(16) unsigned int hls1[52];

  // ---- stage w_ih -> wlds (f16, K padded to 128 with zeros) ----
  for (int i = tid; i < 400 * 25; i += 512) {
    int row = i / 25;
    int q = i - row * 25;
    const float4 v = *(const float4*)(w_ih + (size_t)row * DD + 4 * q);
    wlds[row * 68 + 2 * q]     = pk(v.x, v.y);
    wlds[row * 68 + 2 * q + 1] = pk(v.z, v.w);
  }
  for (int i = tid; i < 400 * 18; i += 512) {
    int row = i / 18;
    int d = i - row * 18;
    wlds[row * 68 + 50 + d] = 0u;
  }
  for (int i = tid; i < TS * 18; i += 512) {
    int row = i / 18;
    int d = i - row * 18;
    xlds[row * 68 + 50 + d] = 0u;
  }

  // ---- scan state (v6) ----
  const bool uact = tid < NG;
  const int j = tid >> 2;
  const int s = tid & 3;
  const int od = 12 * s;
  const int nnv = (s == 3) ? 14 : 12;

  h2_t wA[14], wB[14], wC[14], wD[14];
  float bias = 0.f;
  if (uact) {
#pragma unroll
    for (int d = 0; d < 14; ++d) {
      int dd = (d < nnv) ? (od + d) : 0;
      const float* r0 = w_hh + (size_t)(0 * 100 + j) * HH + 2 * dd;
      const float* r1 = w_hh + (size_t)(1 * 100 + j) * HH + 2 * dd;
      const float* r2 = w_hh + (size_t)(2 * 100 + j) * HH + 2 * dd;
      const float* r3 = w_hh + (size_t)(3 * 100 + j) * HH + 2 * dd;
      h2_t z = __builtin_amdgcn_cvt_pkrtz(0.f, 0.f);
      wA[d] = (d < nnv) ? __builtin_amdgcn_cvt_pkrtz(r0[0], r0[1]) : z;
      wB[d] = (d < nnv) ? __builtin_amdgcn_cvt_pkrtz(r1[0], r1[1]) : z;
      wC[d] = (d < nnv) ? __builtin_amdgcn_cvt_pkrtz(r2[0], r2[1]) : z;
      wD[d] = (d < nnv) ? __builtin_amdgcn_cvt_pkrtz(r3[0], r3[1]) : z;
    }
    bias = b_ih[s * 100 + j] + b_hh[s * 100 + j];
  }
  const float kk2 = (s == 2) ? (2.f * F_LOG2E) : (-F_LOG2E);
  const float cA  = (s == 2) ? -2.f : 1.f;
  const float cB  = (s == 2) ? 1.f : 0.f;

  // emission lanes: wave 7
  const int el = tid - 448;
  const bool eact = (el >= 0) && (el < 50);
  const int l  = (el >= 0) ? (el >> 1) : 0;
  const int hf = (el >= 0) ? (el & 1) : 0;
  const int eo = hf ? 24 : 0;
  const int en = hf ? 26 : 24;
  h2_t wt[26];
  float bt = 0.f;
  if (eact) {
    const float* wr = w_tag + (size_t)l * 200 + dir * 100;
#pragma unroll
    for (int d = 0; d < 26; ++d) {
      int dd = (d < en) ? (eo + d) : 0;
      h2_t z = __builtin_amdgcn_cvt_pkrtz(0.f, 0.f);
      wt[d] = (d < en) ? __builtin_amdgcn_cvt_pkrtz(wr[2 * dd], wr[2 * dd + 1]) : z;
    }
    if (dir == 0 && hf == 0) bt = b_tag[l];
  }
  float* emo = dir ? em_b : em_f;
  float* emp = emo + ((size_t)b * TT + (dir ? (TT - 1) : 0)) * LL + l;
  const ptrdiff_t estep = dir ? -(ptrdiff_t)LL : (ptrdiff_t)LL;

  if (tid < 52) { hls0[tid] = 0u; hls1[tid] = 0u; }

  // burst lane mapping
  const int wv   = tid >> 6;
  const int lane = tid & 63;
  const int l16  = lane & 15;
  const int quad = lane >> 4;
  const int c0b  = (25 * wv) >> 3;
  const int c1b  = (25 * (wv + 1)) >> 3;

  // x staging mapping: thread t<416 covers (row = t/13, seg = t%13)
  const int tprow = tid / 13;
  const int tps   = tid - 13 * tprow;
  const bool tp_act = tid < 416;

  // initial x prefetch (tile 0)
  float4 xa = {0, 0, 0, 0}, xb = {0, 0, 0, 0};
  if (tp_act) {
    int ii = tprow;
    int tt = dir ? (TT - 1 - ii) : ii;
    int tk = tok[b * TT + tt];
    const float* xp = emb + (size_t)tk * DD + 8 * tps;
    xa = *(const float4*)xp;
    if (tps < 12) xb = *(const float4*)(xp + 4);
  }

  float c = 0.f;
  unsigned short gnext = 0;
  int grow = 0;

#define SDOT(d, hh) \
  p0 = fdot2(wA[d], bc_h2(hh), p0); p1 = fdot2(wB[d], bc_h2(hh), p1); \
  p2 = fdot2(wC[d], bc_h2(hh), p2); p3 = fdot2(wD[d], bc_h2(hh), p3);
#define EDOT(d, hh) { h2_t h = bc_h2(hh); \
  if ((d & 3) == 0) a0 = fdot2(wt[d], h, a0); \
  else if ((d & 3) == 1) a1 = fdot2(wt[d], h, a1); \
  else if ((d & 3) == 2) a2 = fdot2(wt[d], h, a2); \
  else a3 = fdot2(wt[d], h, a3); }

#define SCAN_STEP(HRD, HWR, TVNZ)                                          \
  {                                                                        \
    if (uact) {                                                            \
      unsigned short gcurr = gnext;                                        \
      int nr = (grow < TS - 1) ? grow + 1 : TS - 1;                        \
      gnext = gin_lds[nr * 400 + tid];                                     \
      grow = nr;                                                           \
      const unsigned int* hp = (HRD) + od;                                 \
      uint4 u0 = *((const uint4*)hp);                                      \
      uint4 u1 = *((const uint4*)(hp + 4));                                \
      uint4 u2 = *((const uint4*)(hp + 8));                                \
      uint2 u3 = *((const uint2*)(hp + 12));                               \
      float p0, p1, p2, p3;                                                \
      p0 = fdot2(wA[0], bc_h2(u0.x), 0.f);                                 \
      p1 = fdot2(wB[0], bc_h2(u0.x), 0.f);                                 \
      p2 = fdot2(wC[0], bc_h2(u0.x), 0.f);                                 \
      p3 = fdot2(wD[0], bc_h2(u0.x), 0.f);                                 \
      SDOT(1, u0.y)  SDOT(2, u0.z)  SDOT(3, u0.w)                          \
      SDOT(4, u1.x)  SDOT(5, u1.y)  SDOT(6, u1.z)  SDOT(7, u1.w)           \
      SDOT(8, u2.x)  SDOT(9, u2.y)  SDOT(10, u2.z) SDOT(11, u2.w)          \
      SDOT(12, u3.x) SDOT(13, u3.y)                                        \
      p0 = qadd<78>(qadd<177>(p0));                                        \
      p1 = qadd<78>(qadd<177>(p1));                                        \
      p2 = qadd<78>(qadd<177>(p2));                                        \
      p3 = qadd<78>(qadd<177>(p3));                                        \
      float psel = (s == 0) ? p0 : (s == 1) ? p1 : (s == 2) ? p2 : p3;     \
      float gate = psel + bias + (float)__builtin_bit_cast(__fp16, gcurr); \
      float y  = fexp2(kk2 * gate);                                        \
      float rr = frcp(1.f + y);                                            \
      float actv = fmaf(cA, rr, cB);                                       \
      float iv = qbcast<0>(actv);                                          \
      float fv = qbcast<1>(actv);                                          \
      float gv = qbcast<2>(actv);                                          \
      float ov = qbcast<3>(actv);                                          \
      c = fmaf(fv, c, iv * gv);                                            \
      float hvv = ov * tanh_f(c);                                          \
      if (s == 0) ((__fp16*)(HWR))[j] = (__fp16)hvv;                       \
    } else if (eact && (TVNZ)) {                                           \
      const unsigned int* hp = (HRD) + eo;                                 \
      uint4 e0 = *((const uint4*)hp);                                      \
      uint4 e1 = *((const uint4*)(hp + 4));                                \
      uint4 e2 = *((const uint4*)(hp + 8));                                \
      uint4 e3 = *((const uint4*)(hp + 12));                               \
      uint4 e4 = *((const uint4*)(hp + 16));                               \
      uint4 e5 = *((const uint4*)(hp + 20));                               \
      uint2 e6 = *((const uint2*)(hp + 24));                               \
      float a0, a1, a2, a3;                                                \
      a0 = fdot2(wt[0], bc_h2(e0.x), 0.f);                                 \
      a1 = fdot2(wt[1], bc_h2(e0.y), 0.f);                                 \
      a2 = fdot2(wt[2], bc_h2(e0.z), 0.f);                                 \
      a3 = fdot2(wt[3], bc_h2(e0.w), 0.f);                                 \
      EDOT(4, e1.x)  EDOT(5, e1.y)  EDOT(6, e1.z)  EDOT(7, e1.w)           \
      EDOT(8, e2.x)  EDOT(9, e2.y)  EDOT(10, e2.z) EDOT(11, e2.w)          \
      EDOT(12, e3.x) EDOT(13, e3.y) EDOT(14, e3.z) EDOT(15, e3.w)          \
      EDOT(16, e4.x) EDOT(17, e4.y) EDOT(18, e4.z) EDOT(19, e4.w)          \
      EDOT(20, e5.x) EDOT(21, e5.y) EDOT(22, e5.z) EDOT(23, e5.w)          \
      EDOT(24, e6.x) EDOT(25, e6.y)                                        \
      float ss = (a0 + a1) + (a2 + a3);                                    \
      float tot = qadd<177>(ss);                                           \
      if (hf == 0) *emp = tot + bt;                                        \
      emp += estep;                                                        \
    }                                                                      \
    lds_barrier();                                                         \
  }

  __syncthreads();  // wlds / xlds-pad / hls init complete

  for (int T = 0; T < NTILE; ++T) {
    // ---- write prefetched x regs to xlds ----
    if (tp_act) {
      unsigned int* xr = xlds + tprow * 68 + 4 * tps;
      if (tps < 12) {
        uint4 u;
        u.x = pk(xa.x, xa.y); u.y = pk(xa.z, xa.w);
        u.z = pk(xb.x, xb.y); u.w = pk(xb.z, xb.w);
        *(uint4*)xr = u;
      } else {
        xr[0] = pk(xa.x, xa.y);
        xr[1] = pk(xa.z, xa.w);
      }
    }
    __syncthreads();

    // ---- BURST ----
    {
      v8h af[2][4];
#pragma unroll
      for (int rg = 0; rg < 2; ++rg)
#pragma unroll
        for (int f = 0; f < 4; ++f)
          af[rg][f] = __builtin_bit_cast(v8h,
              *(const uint4*)(xlds + (rg * 16 + l16) * 68 + f * 16 + quad * 4));

      // kick off next tile's x prefetch (stays in flight through the scan)
      if (tp_act && T + 1 < NTILE) {
        int ii = (T + 1) * TS + tprow;
        int tt = dir ? (TT - 1 - ii) : ii;
        int tk = tok[b * TT + tt];
        const float* xp = emb + (size_t)tk * DD + 8 * tps;
        xa = *(const float4*)xp;
        if (tps < 12) xb = *(const float4*)(xp + 4);
      }

      __fp16* gout = (__fp16*)gin_lds;
      for (int cc = c0b; cc < c1b; ++cc) {
        const int n = 16 * cc + l16;
        const unsigned int* wp = wlds + n * 68 + quad * 4;
        v8h bf0 = __builtin_bit_cast(v8h, *(const uint4*)(wp));
        v8h bf1 = __builtin_bit_cast(v8h, *(const uint4*)(wp + 16));
        v8h bf2 = __builtin_bit_cast(v8h, *(const uint4*)(wp + 32));
        v8h bf3 = __builtin_bit_cast(v8h, *(const uint4*)(wp + 48));
        const int qn = (n * 41) >> 12;
        const int p  = ((n - 100 * qn) << 2) + qn;
#pragma unroll
        for (int rg = 0; rg < 2; ++rg) {
          v4f acc = {0.f, 0.f, 0.f, 0.f};
          acc = __builtin_amdgcn_mfma_f32_16x16x32_f16(af[rg][0], bf0, acc, 0, 0, 0);
          acc = __builtin_amdgcn_mfma_f32_16x16x32_f16(af[rg][1], bf1, acc, 0, 0, 0);
          acc = __builtin_amdgcn_mfma_f32_16x16x32_f16(af[rg][2], bf2, acc, 0, 0, 0);
          acc = __builtin_amdgcn_mfma_f32_16x16x32_f16(af[rg][3], bf3, acc, 0, 0, 0);
          const int rowb = rg * 16 + quad * 4;
#pragma unroll
          for (int r = 0; r < 4; ++r)
            gout[(rowb + r) * 400 + p] = (__fp16)acc[r];
        }
      }
    }
    __syncthreads();
    if (uact) { grow = 0; gnext = gin_lds[tid]; }

    // ---- TS scan steps ----
    SCAN_STEP(hls0, hls1, (T > 0))
    SCAN_STEP(hls1, hls0, true)
    for (int it = 1; it < TS / 2; ++it) {
      SCAN_STEP(hls0, hls1, true)
      SCAN_STEP(hls1, hls0, true)
    }
  }
#undef SCAN_STEP
#undef SDOT

  // epilogue: emission for the last h (in hls0)
  if (eact) {
    const unsigned int* hp = hls0 + eo;
    uint4 e0 = *((const uint4*)hp);
    uint4 e1 = *((const uint4*)(hp + 4));
    uint4 e2 = *((const uint4*)(hp + 8));
    uint4 e3 = *((const uint4*)(hp + 12));
    uint4 e4 = *((const uint4*)(hp + 16));
    uint4 e5 = *((const uint4*)(hp + 20));
    uint2 e6 = *((const uint2*)(hp + 24));
    float a0, a1, a2, a3;
    a0 = fdot2(wt[0], bc_h2(e0.x), 0.f);
    a1 = fdot2(wt[1], bc_h2(e0.y), 0.f);
    a2 = fdot2(wt[2], bc_h2(e0.z), 0.f);
    a3 = fdot2(wt[3], bc_h2(e0.w), 0.f);
    EDOT(4, e1.x)  EDOT(5, e1.y)  EDOT(6, e1.z)  EDOT(7, e1.w)
    EDOT(8, e2.x)  EDOT(9, e2.y)  EDOT(10, e2.z) EDOT(11, e2.w)
    EDOT(12, e3.x) EDOT(13, e3.y) EDOT(14, e3.z) EDOT(15, e3.w)
    EDOT(16, e4.x) EDOT(17, e4.y) EDOT(18, e4.z) EDOT(19, e4.w)
    EDOT(20, e5.x) EDOT(21, e5.y) EDOT(22, e5.z) EDOT(23, e5.w)
    EDOT(24, e6.x) EDOT(25, e6.y)
    float ss = (a0 + a1) + (a2 + a3);
    float tot = qadd<177>(ss);
    if (hf == 0) {
      int ttp = dir ? 0 : (TT - 1);
      emo[((size_t)b * TT + ttp) * LL + l] = tot + bt;
    }
  }
#undef EDOT
}

// ---------------------------------------------------------------------------
// FALLBACK scan (small ws): writes hc16 f16.
// ---------------------------------------------------------------------------
__global__ __launch_bounds__(512, 2) void lstm_scan_fb(
    const int* __restrict__ tok, const float* __restrict__ emb,
    const float* __restrict__ w_ih_f, const float* __restrict__ w_hh_f,
    const float* __restrict__ b_ih_f, const float* __restrict__ b_hh_f,
    const float* __restrict__ w_ih_b, const float* __restrict__ w_hh_b,
    const float* __restrict__ b_ih_b, const float* __restrict__ b_hh_b,
    unsigned short* __restrict__ hc16)
{
  const int tid = threadIdx.x;
  const int b   = blockIdx.x & 127;
  const int dir = blockIdx.x >> 7;

  const float* w_ih = dir ? w_ih_b : w_ih_f;
  const float* w_hh = dir ? w_hh_b : w_hh_f;
  const float* b_ih = dir ? b_ih_b : b_ih_f;
  const float* b_hh = dir ? b_hh_b : b_hh_f;

  __shared__ __align__(16) unsigned int xs[2][64];
  __shared__ __align__(16) unsigned int hls[64];
  __shared__ float gl[NG];

  h2_t wih[50], whh[50];
  float bias = 0.f;
  if (tid < NG) {
    const float4* wi = (const float4*)(w_ih + tid * DD);
    const float4* wh = (const float4*)(w_hh + tid * DD);
#pragma unroll
    for (int kk = 0; kk < 25; ++kk) {
      float4 a = wi[kk];
      wih[2 * kk]     = __builtin_amdgcn_cvt_pkrtz(a.x, a.y);
      wih[2 * kk + 1] = __builtin_amdgcn_cvt_pkrtz(a.z, a.w);
      float4 c = wh[kk];
      whh[2 * kk]     = __builtin_amdgcn_cvt_pkrtz(c.x, c.y);
      whh[2 * kk + 1] = __builtin_amdgcn_cvt_pkrtz(c.z, c.w);
    }
    bias = b_ih[tid] + b_hh[tid];
  }
  if (tid < 2) { xs[0][50 + tid] = 0u; xs[1][50 + tid] = 0u; hls[50 + tid] = 0u; }
  if (tid < 50) hls[tid] = 0u;

  const int base = b * TT;
  if (tid >= 448 && tid < 498) {
    int tt0 = dir ? (TT - 1) : 0;
    int i = tid - 448;
    int tk = tok[base + tt0];
    float2 v = ((const float2*)(emb + (size_t)tk * DD))[i];
    xs[0][i] = pk(v.x, v.y);
  }
  __syncthreads();

  float cst = 0.f;
  unsigned short* hcb = hc16 + (size_t)base * 200 + dir * 100;

  for (int t = 0; t < TT; ++t) {
    const int buf = t & 1;
    const int tt  = dir ? (TT - 1 - t) : t;

    if (tid < NG) {
      float a0 = bias, a1 = 0.f, a2 = 0.f, a3 = 0.f;
      const unsigned int* xp = xs[buf];
#pragma unroll
      for (int g = 0; g < 13; ++g) {
        uint4 u = ((const uint4*)xp)[g];
        const int k = 4 * g;
        a0 = fdot2(wih[k], bc_h2(u.x), a0);
        a1 = fdot2(wih[k + 1], bc_h2(u.y), a1);
        if (k + 2 < 50) a2 = fdot2(wih[k + 2], bc_h2(u.z), a2);
        if (k + 3 < 50) a3 = fdot2(wih[k + 3], bc_h2(u.w), a3);
      }
#pragma unroll
      for (int g = 0; g < 13; ++g) {
        uint4 u = ((const uint4*)hls)[g];
        const int k = 4 * g;
        a0 = fdot2(whh[k], bc_h2(u.x), a0);
        a1 = fdot2(whh[k + 1], bc_h2(u.y), a1);
        if (k + 2 < 50) a2 = fdot2(whh[k + 2], bc_h2(u.z), a2);
        if (k + 3 < 50) a3 = fdot2(whh[k + 3], bc_h2(u.w), a3);
      }
      float accs = (a0 + a1) + (a2 + a3);
      float av = (tid >= 200 && tid < 300) ? tanh_f(accs) : sigmoid_f(accs);
      gl[tid] = av;
    } else if (tid >= 448 && tid < 498 && t < TT - 1) {
      int ttn = dir ? (TT - 2 - t) : (t + 1);
      int i = tid - 448;
      int tk = tok[base + ttn];
      float2 v = ((const float2*)(emb + (size_t)tk * DD))[i];
      xs[buf ^ 1][i] = pk(v.x, v.y);
    }
    __syncthreads();

    if (tid < HH) {
      float gi = gl[tid], gf = gl[tid + 100], gg = gl[tid + 200], go = gl[tid + 300];
      cst = gf * cst + gi * gg;
      float hv = go * tanh_f(cst);
      __fp16 h16 = (__fp16)hv;
      ((__fp16*)hls)[tid] = h16;
      hcb[(size_t)tt * 200 + tid] = __builtin_bit_cast(unsigned short, h16);
    }
    __syncthreads();
  }
}

// Fallback emissions kernel.
__global__ __launch_bounds__(256, 2) void emis2(
    const unsigned short* __restrict__ hc16, const float* __restrict__ w_tag,
    const float* __restrict__ b_tag, float* __restrict__ em)
{
  __shared__ unsigned int hsh[64 * 101];
  __shared__ unsigned int wsh[25 * 100];
  const int tid = threadIdx.x;
  const size_t m0 = (size_t)blockIdx.x * 64;

  const unsigned int* hcu = (const unsigned int*)hc16;
  for (int i = tid; i < 64 * 100; i += 256) {
    int r = i / 100;
    int k = i - r * 100;
    hsh[r * 101 + k] = hcu[m0 * 100 + i];
  }
  for (int i = tid; i < 25 * 100; i += 256) {
    float2 wv = ((const float2*)w_tag)[i];
    wsh[i] = pk(wv.x, wv.y);
  }
  __syncthreads();

  const int r = tid & 63, q = tid >> 6;
  int lidx[7];
  bool lv[7];
  float acc[7];
#pragma unroll
  for (int ii = 0; ii < 7; ++ii) {
    int l = q + 4 * ii;
    lv[ii] = (l < LL);
    lidx[ii] = lv[ii] ? l : 0;
    acc[ii] = lv[ii] ? b_tag[lidx[ii]] : 0.f;
  }
  const unsigned int* hrow = hsh + r * 101;
#pragma unroll 2
  for (int k = 0; k < 100; ++k) {
    h2_t hv = bc_h2(hrow[k]);
#pragma unroll
    for (int ii = 0; ii < 7; ++ii)
      acc[ii] = fdot2(hv, bc_h2(wsh[lidx[ii] * 100 + k]), acc[ii]);
  }
#pragma unroll
  for (int ii = 0; ii < 7; ++ii)
    if (lv[ii]) em[(m0 + r) * LL + lidx[ii]] = acc[ii];
}

// ---------------------------------------------------------------------------
// CRF all-in-one: block b = batch elem, 192 threads = 3 waves.
// Wave 0 = forward alpha (t=0..255), wave 1 = backward beta (t=511..256),
// wave 2 = gold path score. LDS-combine -> atomicAdd(out, logZ - gold).
// d_out must be pre-zeroed by the host launch (hipMemsetAsync).
// ---------------------------------------------------------------------------
__global__ __launch_bounds__(192) void crf_all(
    const float* __restrict__ em_f, const float* __restrict__ em_b,
    const int* __restrict__ tags, const int* __restrict__ lengths,
    const float* __restrict__ trans,
    const float* __restrict__ startt, const float* __restrict__ endt,
    float* __restrict__ out)
{
  const int tid = threadIdx.x;
  const int b   = blockIdx.x;
  const int w   = tid >> 6;
  const int lane = tid & 63;

  __shared__ float abf[LL], abb[LL];
  __shared__ float gd;

  if (w < 2) {
    const int side = w;
    const int j = (lane < LL) ? lane : 0;
    const float* ef = em_f + (size_t)b * TT * LL;
    const float* eb = em_b + (size_t)b * TT * LL;

    float E[LL];
#pragma unroll
    for (int i = 0; i < LL; ++i) {
      float tv = (side == 0 ? trans[i * LL + j] : trans[j * LL + i]);
      E[i] = fexp2(tv * F_LOG2E);
    }

    float a, C = 0.f;
    if (side == 0) {
      a = (startt[j] + ef[j] + eb[j]) * F_LOG2E;
      float efA = ef[LL + j],     ebA = eb[LL + j];
      float efB = ef[2 * LL + j], ebB = eb[2 * LL + j];
      for (int t = 1; t < 256; ++t) {
        float em2 = (efA + ebA) * F_LOG2E;
        int tn = (t + 2 < 256) ? (t + 2) : 255;
        efA = efB; ebA = ebB;
        efB = ef[(size_t)tn * LL + j];
        ebB = eb[(size_t)tn * LL + j];
        float sh = rfl(a);
        C += sh;
        float A = fexp2(a - sh);
        float s0 = 0.f, s1 = 0.f, s2 = 0.f, s3 = 0.f;
#pragma unroll
        for (int i = 0; i < LL; ++i) {
          float Ai = bperm(A, 4 * i);
          if ((i & 3) == 0) s0 = fmaf(Ai, E[i], s0);
          else if ((i & 3) == 1) s1 = fmaf(Ai, E[i], s1);
          else if ((i & 3) == 2) s2 = fmaf(Ai, E[i], s2);
          else s3 = fmaf(Ai, E[i], s3);
        }
        a = flog2((s0 + s1) + (s2 + s3)) + em2;
      }
    } else {
      a = endt[j] * F_LOG2E;
      float efA = ef[(size_t)(TT - 1) * LL + j], ebA = eb[(size_t)(TT - 1) * LL + j];
      float efB = ef[(size_t)(TT - 2) * LL + j], ebB = eb[(size_t)(TT - 2) * LL + j];
      for (int stpi = 0; stpi < 256; ++stpi) {
        float em2 = (efA + ebA) * F_LOG2E;
        int t1n = (stpi + 2 < 256) ? (TT - 3 - stpi) : 256;
        efA = efB; ebA = ebB;
        efB = ef[(size_t)t1n * LL + j];
        ebB = eb[(size_t)t1n * LL + j];
        float v = a + em2;
        float sh = rfl(v);
        C += sh;
        float A = fexp2(v - sh);
        float s0 = 0.f, s1 = 0.f, s2 = 0.f, s3 = 0.f;
#pragma unroll
        for (int i = 0; i < LL; ++i) {
          float Ai = bperm(A, 4 * i);
          if ((i & 3) == 0) s0 = fmaf(Ai, E[i], s0);
          else if ((i & 3) == 1) s1 = fmaf(Ai, E[i], s1);
          else if ((i & 3) == 2) s2 = fmaf(Ai, E[i], s2);
          else s3 = fmaf(Ai, E[i], s3);
        }
        a = flog2((s0 + s1) + (s2 + s3));
      }
    }
    if (lane < LL) {
      if (side == 0) abf[lane] = a + C;   // log2 domain
      else          abb[lane] = a + C;
    }
  } else {
    const int len = lengths[b];
    float acc = 0.f;
#pragma unroll
    for (int k = 0; k < 8; ++k) {
      int t = k * 64 + lane;
      int tg = tags[b * TT + t];
      size_t ei = ((size_t)b * TT + t) * LL + tg;
      float e = em_f[ei] + em_b[ei];
      float term;
      if (t == 0) term = startt[tg] + e;
      else        term = trans[tags[b * TT + t - 1] * LL + tg] + e;
      if (t == len - 1) term += endt[tg];
      if (t < len) acc += term;
    }
    for (int o = 32; o > 0; o >>= 1) acc += __shfl_down(acc, o);
    if (lane == 0) gd = acc;
  }
  __syncthreads();

  if (tid < 64) {
    float v = (tid < LL) ? (abf[tid] + abb[tid]) : -1e30f;
    float m = v;
    for (int o = 32; o > 0; o >>= 1) m = fmaxf(m, __shfl_down(m, o));
    m = rfl(m);
    float e = (tid < LL) ? fexp2(v - m) : 0.f;
    for (int o = 32; o > 0; o >>= 1) e += __shfl_down(e, o);
    if (tid == 0)
      atomicAdd(out, (m + flog2(e)) * F_LN2 - gd);
  }
}

extern "C" void kernel_launch(void* const* d_in, const int* in_sizes, int n_in,
                              void* d_out, int out_size, void* d_ws, size_t ws_size,
                              hipStream_t stream) {
  const int*   tok   = (const int*)d_in[0];
  const int*   tags  = (const int*)d_in[1];
  const int*   lens  = (const int*)d_in[2];
  const float* emb   = (const float*)d_in[3];
  const float* wif   = (const float*)d_in[4];
  const float* whf   = (const float*)d_in[5];
  const float* bif   = (const float*)d_in[6];
  const float* bhf   = (const float*)d_in[7];
  const float* wib   = (const float*)d_in[8];
  const float* whb   = (const float*)d_in[9];
  const float* bib   = (const float*)d_in[10];
  const float* bhb   = (const float*)d_in[11];
  const float* wtag  = (const float*)d_in[12];
  const float* btag  = (const float*)d_in[13];
  const float* trans = (const float*)d_in[14];
  const float* st    = (const float*)d_in[15];
  const float* en    = (const float*)d_in[16];

  char* wsb = (char*)d_ws;
  float* em_f = (float*)wsb;                                   //  6,553,600 B
  float* em_b = (float*)(wsb + 6553600);                       //  6,553,600 B
  const size_t need_fused = 13107200ULL;
  const size_t need_fb    = 13107200ULL + 26214400ULL;

  hipMemsetAsync(d_out, 0, sizeof(float), stream);

  if (ws_size >= need_fused && ws_size < need_fb) {
    lstm_fused2<<<256, 512, 0, stream>>>(tok, emb, wif, wib, bif, bhf, bib, bhb,
                                         whf, whb, wtag, btag, em_f, em_b);
  } else if (ws_size >= need_fb) {
    lstm_fused2<<<256, 512, 0, stream>>>(tok, emb, wif, wib, bif, bhf, bib, bhb,
                                         whf, whb, wtag, btag, em_f, em_b);
  } else {
    // tiny-ws fallback (should not occur)
    unsigned short* hc16 = (unsigned short*)(wsb + 13107200);
    hipMemsetAsync(em_b, 0, 6553600, stream);
    lstm_scan_fb<<<256, 512, 0, stream>>>(tok, emb, wif, whf, bif, bhf,
                                          wib, whb, bib, bhb, hc16);
    emis2<<<1024, 256, 0, stream>>>(hc16, wtag, btag, em_f);
  }
  crf_all<<<128, 192, 0, stream>>>(em_f, em_b, tags, lens, trans, st, en,
                                   (float*)d_out);
}

// Round 11
// 425.414 us; speedup vs baseline: 1.2796x; 1.0181x over previous
//
#include <hip/hip_runtime.h>
#include <cstdint>
#include <cstddef>

#define BB 128
#define TT 512
#define DD 100
#define HH 100
#define NG 400   // 4*H
#define LL 25
#define TS 32    // scan tile (steps per burst)
#define NTILE 16
#define F_LOG2E 1.44269504088896340736f
#define F_LN2   0.69314718055994530942f

typedef __decltype(__builtin_amdgcn_cvt_pkrtz(0.f, 0.f)) h2_t;
typedef _Float16 v8h __attribute__((ext_vector_type(8)));
typedef float v4f __attribute__((ext_vector_type(4)));

__device__ __forceinline__ h2_t bc_h2(unsigned int u) {
  return __builtin_bit_cast(h2_t, u);
}
__device__ __forceinline__ unsigned int pk(float x, float y) {
  return __builtin_bit_cast(unsigned int, __builtin_amdgcn_cvt_pkrtz(x, y));
}

__device__ __forceinline__ float fdot2(h2_t a, h2_t b, float c) {
#if __has_builtin(__builtin_amdgcn_fdot2)
  return __builtin_amdgcn_fdot2(a, b, c, false);
#else
  return c + (float)a[0] * (float)b[0] + (float)a[1] * (float)b[1];
#endif
}

__device__ __forceinline__ float fexp2(float x) { return __builtin_amdgcn_exp2f(x); }
__device__ __forceinline__ float flog2(float x) { return __builtin_amdgcn_logf(x); }
__device__ __forceinline__ float frcp(float x)  { return __builtin_amdgcn_rcpf(x); }

__device__ __forceinline__ float sigmoid_f(float x) {
  return frcp(1.f + fexp2(-F_LOG2E * x));
}
__device__ __forceinline__ float tanh_f(float x) {
  float e = fexp2(2.f * F_LOG2E * x);
  return 1.f - 2.f * frcp(e + 1.f);
}

template <int CTRL>
__device__ __forceinline__ float qadd(float v) {
#if __has_builtin(__builtin_amdgcn_mov_dpp)
  int m = __builtin_amdgcn_mov_dpp(__builtin_bit_cast(int, v), CTRL, 0xF, 0xF, true);
  return v + __builtin_bit_cast(float, m);
#else
  int x = (CTRL == 177) ? 1 : 2;
  return v + __shfl_xor(v, x);
#endif
}

template <int LANE>
__device__ __forceinline__ float qbcast(float v) {
#if __has_builtin(__builtin_amdgcn_mov_dpp)
  int m = __builtin_amdgcn_mov_dpp(__builtin_bit_cast(int, v), LANE * 0x55, 0xF, 0xF, true);
  return __builtin_bit_cast(float, m);
#else
  return __shfl(v, (threadIdx.x & 63 & ~3) + LANE);
#endif
}

__device__ __forceinline__ float rfl(float v) {
  return __builtin_bit_cast(float,
      __builtin_amdgcn_readfirstlane(__builtin_bit_cast(int, v)));
}

__device__ __forceinline__ void wave_fence() {
#if __has_builtin(__builtin_amdgcn_wave_barrier)
  __builtin_amdgcn_wave_barrier();
#endif
}

// LDS-visibility-only barrier (vmcnt left free): imm 0xC07F.
__device__ __forceinline__ void lds_barrier() {
  __builtin_amdgcn_s_waitcnt(0xC07F);
  __builtin_amdgcn_s_barrier();
}

// ---------------------------------------------------------------------------
// FUSED BiLSTM + x-GEMM + emissions, v3. One block per (batch, dir), 512 thr.
// B-fragments of w_ih live in REGISTERS (per-lane, one-time global load);
// x tiles (32 steps) register-prefetched one tile early -> xlds. BURST: wave
// w owns 3-4 B-columns x 2 m-tiles, A frags from xlds, mfma_16x16x32_f16,
// store perm p(n)=4*(n%100)+n/100 into gin_lds. SCAN: v6 structure.
// LDS ~35 KB (no w_ih array).
// ---------------------------------------------------------------------------
__global__ __launch_bounds__(512, 2) void lstm_fused3(
    const int* __restrict__ tok, const float* __restrict__ emb,
    const float* __restrict__ w_ih_f, const float* __restrict__ w_ih_b,
    const float* __restrict__ b_ih_f, const float* __restrict__ b_hh_f,
    const float* __restrict__ b_ih_b, const float* __restrict__ b_hh_b,
    const float* __restrict__ w_hh_f, const float* __restrict__ w_hh_b,
    const float* __restrict__ w_tag, const float* __restrict__ b_tag,
    float* __restrict__ em_f, float* __restrict__ em_b)
{
  const int tid = threadIdx.x;
  const int b   = blockIdx.x & 127;
  const int dir = blockIdx.x >> 7;
  const float* w_hh = dir ? w_hh_b : w_hh_f;
  const float* w_ih = dir ? w_ih_b : w_ih_f;
  const float* b_ih = dir ? b_ih_b : b_ih_f;
  const float* b_hh = dir ? b_hh_b : b_hh_f;

  __shared__ __align__(16) unsigned short gin_lds[TS * 400];   // 25.6 KB
  __shared__ __align__(16) unsigned int xlds[TS * 68];         // 8.7 KB
  __shared__ __align__(16) unsigned int hls0[52];
  __shared__ __align__(16) unsigned int hls1[52];

  // burst lane mapping
  const int wv   = tid >> 6;
  const int lane = tid & 63;
  const int l16  = lane & 15;
  const int quad = lane >> 4;
  const int c0b  = (25 * wv) >> 3;
  const int c1b  = (25 * (wv + 1)) >> 3;
  const int ncol = c1b - c0b;   // 3 or 4

  // ---- one-time: B fragments from global w_ih into registers ----
  v8h bfr[4][4];
  int pcol[4];
#pragma unroll
  for (int ci = 0; ci < 4; ++ci) {
    const int cc = (ci < ncol) ? (c0b + ci) : c0b;
    const int n  = 16 * cc + l16;
    const float* wr = w_ih + (size_t)n * DD;
#pragma unroll
    for (int f = 0; f < 3; ++f) {
      const float* wp = wr + f * 32 + quad * 8;
      float4 va = *(const float4*)(wp);
      float4 vb = *(const float4*)(wp + 4);
      uint4 u;
      u.x = pk(va.x, va.y); u.y = pk(va.z, va.w);
      u.z = pk(vb.x, vb.y); u.w = pk(vb.z, vb.w);
      bfr[ci][f] = __builtin_bit_cast(v8h, u);
    }
    {
      uint4 u = {0u, 0u, 0u, 0u};
      if (quad == 0) {
        float4 va = *(const float4*)(wr + 96);
        u.x = pk(va.x, va.y); u.y = pk(va.z, va.w);
      }
      bfr[ci][3] = __builtin_bit_cast(v8h, u);
    }
    const int qn = (n * 41) >> 12;            // n/100 for n<400
    pcol[ci] = ((n - 100 * qn) << 2) + qn;    // store permutation
  }

  // ---- xlds K-pad zero ----
  for (int i = tid; i < TS * 18; i += 512) {
    int row = i / 18;
    int d = i - row * 18;
    xlds[row * 68 + 50 + d] = 0u;
  }

  // ---- scan state (v6) ----
  const bool uact = tid < NG;
  const int j = tid >> 2;
  const int s = tid & 3;
  const int od = 12 * s;
  const int nnv = (s == 3) ? 14 : 12;

  h2_t wA[14], wB[14], wC[14], wD[14];
  float bias = 0.f;
  if (uact) {
#pragma unroll
    for (int d = 0; d < 14; ++d) {
      int dd = (d < nnv) ? (od + d) : 0;
      const float* r0 = w_hh + (size_t)(0 * 100 + j) * HH + 2 * dd;
      const float* r1 = w_hh + (size_t)(1 * 100 + j) * HH + 2 * dd;
      const float* r2 = w_hh + (size_t)(2 * 100 + j) * HH + 2 * dd;
      const float* r3 = w_hh + (size_t)(3 * 100 + j) * HH + 2 * dd;
      h2_t z = __builtin_amdgcn_cvt_pkrtz(0.f, 0.f);
      wA[d] = (d < nnv) ? __builtin_amdgcn_cvt_pkrtz(r0[0], r0[1]) : z;
      wB[d] = (d < nnv) ? __builtin_amdgcn_cvt_pkrtz(r1[0], r1[1]) : z;
      wC[d] = (d < nnv) ? __builtin_amdgcn_cvt_pkrtz(r2[0], r2[1]) : z;
      wD[d] = (d < nnv) ? __builtin_amdgcn_cvt_pkrtz(r3[0], r3[1]) : z;
    }
    bias = b_ih[s * 100 + j] + b_hh[s * 100 + j];
  }
  const float kk2 = (s == 2) ? (2.f * F_LOG2E) : (-F_LOG2E);
  const float cA  = (s == 2) ? -2.f : 1.f;
  const float cB  = (s == 2) ? 1.f : 0.f;

  // emission lanes: wave 7
  const int el = tid - 448;
  const bool eact = (el >= 0) && (el < 50);
  const int l  = (el >= 0) ? (el >> 1) : 0;
  const int hf = (el >= 0) ? (el & 1) : 0;
  const int eo = hf ? 24 : 0;
  const int en = hf ? 26 : 24;
  h2_t wt[26];
  float bt = 0.f;
  if (eact) {
    const float* wr = w_tag + (size_t)l * 200 + dir * 100;
#pragma unroll
    for (int d = 0; d < 26; ++d) {
      int dd = (d < en) ? (eo + d) : 0;
      h2_t z = __builtin_amdgcn_cvt_pkrtz(0.f, 0.f);
      wt[d] = (d < en) ? __builtin_amdgcn_cvt_pkrtz(wr[2 * dd], wr[2 * dd + 1]) : z;
    }
    if (dir == 0 && hf == 0) bt = b_tag[l];
  }
  float* emo = dir ? em_b : em_f;
  float* emp = emo + ((size_t)b * TT + (dir ? (TT - 1) : 0)) * LL + l;
  const ptrdiff_t estep = dir ? -(ptrdiff_t)LL : (ptrdiff_t)LL;

  if (tid < 52) { hls0[tid] = 0u; hls1[tid] = 0u; }

  // x staging mapping: thread t<416 covers (row = t/13, seg = t%13)
  const int tprow = tid / 13;
  const int tps   = tid - 13 * tprow;
  const bool tp_act = tid < 416;

  // initial x prefetch (tile 0)
  float4 xa = {0, 0, 0, 0}, xb = {0, 0, 0, 0};
  if (tp_act) {
    int ii = tprow;
    int tt = dir ? (TT - 1 - ii) : ii;
    int tk = tok[b * TT + tt];
    const float* xp = emb + (size_t)tk * DD + 8 * tps;
    xa = *(const float4*)xp;
    if (tps < 12) xb = *(const float4*)(xp + 4);
  }

  float c = 0.f;
  unsigned short gnext = 0;
  int grow = 0;

#define SDOT(d, hh) \
  p0 = fdot2(wA[d], bc_h2(hh), p0); p1 = fdot2(wB[d], bc_h2(hh), p1); \
  p2 = fdot2(wC[d], bc_h2(hh), p2); p3 = fdot2(wD[d], bc_h2(hh), p3);
#define EDOT(d, hh) { h2_t h = bc_h2(hh); \
  if ((d & 3) == 0) a0 = fdot2(wt[d], h, a0); \
  else if ((d & 3) == 1) a1 = fdot2(wt[d], h, a1); \
  else if ((d & 3) == 2) a2 = fdot2(wt[d], h, a2); \
  else a3 = fdot2(wt[d], h, a3); }

#define SCAN_STEP(HRD, HWR, TVNZ)                                          \
  {                                                                        \
    if (uact) {                                                            \
      unsigned short gcurr = gnext;                                        \
      int nr = (grow < TS - 1) ? grow + 1 : TS - 1;                        \
      gnext = gin_lds[nr * 400 + tid];                                     \
      grow = nr;                                                           \
      const unsigned int* hp = (HRD) + od;                                 \
      uint4 u0 = *((const uint4*)hp);                                      \
      uint4 u1 = *((const uint4*)(hp + 4));                                \
      uint4 u2 = *((const uint4*)(hp + 8));                                \
      uint2 u3 = *((const uint2*)(hp + 12));                               \
      float p0, p1, p2, p3;                                                \
      p0 = fdot2(wA[0], bc_h2(u0.x), 0.f);                                 \
      p1 = fdot2(wB[0], bc_h2(u0.x), 0.f);                                 \
      p2 = fdot2(wC[0], bc_h2(u0.x), 0.f);                                 \
      p3 = fdot2(wD[0], bc_h2(u0.x), 0.f);                                 \
      SDOT(1, u0.y)  SDOT(2, u0.z)  SDOT(3, u0.w)                          \
      SDOT(4, u1.x)  SDOT(5, u1.y)  SDOT(6, u1.z)  SDOT(7, u1.w)           \
      SDOT(8, u2.x)  SDOT(9, u2.y)  SDOT(10, u2.z) SDOT(11, u2.w)          \
      SDOT(12, u3.x) SDOT(13, u3.y)                                        \
      p0 = qadd<78>(qadd<177>(p0));                                        \
      p1 = qadd<78>(qadd<177>(p1));                                        \
      p2 = qadd<78>(qadd<177>(p2));                                        \
      p3 = qadd<78>(qadd<177>(p3));                                        \
      float psel = (s == 0) ? p0 : (s == 1) ? p1 : (s == 2) ? p2 : p3;     \
      float gate = psel + bias + (float)__builtin_bit_cast(__fp16, gcurr); \
      float y  = fexp2(kk2 * gate);                                        \
      float rr = frcp(1.f + y);                                            \
      float actv = fmaf(cA, rr, cB);                                       \
      float iv = qbcast<0>(actv);                                          \
      float fv = qbcast<1>(actv);                                          \
      float gv = qbcast<2>(actv);                                          \
      float ov = qbcast<3>(actv);                                          \
      c = fmaf(fv, c, iv * gv);                                            \
      float hvv = ov * tanh_f(c);                                          \
      if (s == 0) ((__fp16*)(HWR))[j] = (__fp16)hvv;                       \
    } else if (eact && (TVNZ)) {                                           \
      const unsigned int* hp = (HRD) + eo;                                 \
      uint4 e0 = *((const uint4*)hp);                                      \
      uint4 e1 = *((const uint4*)(hp + 4));                                \
      uint4 e2 = *((const uint4*)(hp + 8));                                \
      uint4 e3 = *((const uint4*)(hp + 12));                               \
      uint4 e4 = *((const uint4*)(hp + 16));                               \
      uint4 e5 = *((const uint4*)(hp + 20));                               \
      uint2 e6 = *((const uint2*)(hp + 24));                               \
      float a0, a1, a2, a3;                                                \
      a0 = fdot2(wt[0], bc_h2(e0.x), 0.f);                                 \
      a1 = fdot2(wt[1], bc_h2(e0.y), 0.f);                                 \
      a2 = fdot2(wt[2], bc_h2(e0.z), 0.f);                                 \
      a3 = fdot2(wt[3], bc_h2(e0.w), 0.f);                                 \
      EDOT(4, e1.x)  EDOT(5, e1.y)  EDOT(6, e1.z)  EDOT(7, e1.w)           \
      EDOT(8, e2.x)  EDOT(9, e2.y)  EDOT(10, e2.z) EDOT(11, e2.w)          \
      EDOT(12, e3.x) EDOT(13, e3.y) EDOT(14, e3.z) EDOT(15, e3.w)          \
      EDOT(16, e4.x) EDOT(17, e4.y) EDOT(18, e4.z) EDOT(19, e4.w)          \
      EDOT(20, e5.x) EDOT(21, e5.y) EDOT(22, e5.z) EDOT(23, e5.w)          \
      EDOT(24, e6.x) EDOT(25, e6.y)                                        \
      float ss = (a0 + a1) + (a2 + a3);                                    \
      float tot = qadd<177>(ss);                                           \
      if (hf == 0) *emp = tot + bt;                                        \
      emp += estep;                                                        \
    }                                                                      \
    lds_barrier();                                                         \
  }

  __syncthreads();  // xlds-pad / hls init complete

  for (int T = 0; T < NTILE; ++T) {
    // ---- write prefetched x regs to xlds ----
    if (tp_act) {
      unsigned int* xr = xlds + tprow * 68 + 4 * tps;
      if (tps < 12) {
        uint4 u;
        u.x = pk(xa.x, xa.y); u.y = pk(xa.z, xa.w);
        u.z = pk(xb.x, xb.y); u.w = pk(xb.z, xb.w);
        *(uint4*)xr = u;
      } else {
        xr[0] = pk(xa.x, xa.y);
        xr[1] = pk(xa.z, xa.w);
      }
    }
    __syncthreads();

    // ---- BURST ----
    {
      v8h af[2][4];
#pragma unroll
      for (int rg = 0; rg < 2; ++rg)
#pragma unroll
        for (int f = 0; f < 4; ++f)
          af[rg][f] = __builtin_bit_cast(v8h,
              *(const uint4*)(xlds + (rg * 16 + l16) * 68 + f * 16 + quad * 4));

      // kick off next tile's x prefetch (stays in flight through the scan)
      if (tp_act && T + 1 < NTILE) {
        int ii = (T + 1) * TS + tprow;
        int tt = dir ? (TT - 1 - ii) : ii;
        int tk = tok[b * TT + tt];
        const float* xp = emb + (size_t)tk * DD + 8 * tps;
        xa = *(const float4*)xp;
        if (tps < 12) xb = *(const float4*)(xp + 4);
      }

      __fp16* gout = (__fp16*)gin_lds;
#pragma unroll
      for (int ci = 0; ci < 4; ++ci) {
        if (ci >= ncol) break;
        const int p = pcol[ci];
#pragma unroll
        for (int rg = 0; rg < 2; ++rg) {
          v4f acc = {0.f, 0.f, 0.f, 0.f};
          acc = __builtin_amdgcn_mfma_f32_16x16x32_f16(af[rg][0], bfr[ci][0], acc, 0, 0, 0);
          acc = __builtin_amdgcn_mfma_f32_16x16x32_f16(af[rg][1], bfr[ci][1], acc, 0, 0, 0);
          acc = __builtin_amdgcn_mfma_f32_16x16x32_f16(af[rg][2], bfr[ci][2], acc, 0, 0, 0);
          acc = __builtin_amdgcn_mfma_f32_16x16x32_f16(af[rg][3], bfr[ci][3], acc, 0, 0, 0);
          const int rowb = rg * 16 + quad * 4;
#pragma unroll
          for (int r = 0; r < 4; ++r)
            gout[(rowb + r) * 400 + p] = (__fp16)acc[r];
        }
      }
    }
    __syncthreads();
    if (uact) { grow = 0; gnext = gin_lds[tid]; }

    // ---- TS scan steps ----
    SCAN_STEP(hls0, hls1, (T > 0))
    SCAN_STEP(hls1, hls0, true)
    for (int it = 1; it < TS / 2; ++it) {
      SCAN_STEP(hls0, hls1, true)
      SCAN_STEP(hls1, hls0, true)
    }
  }
#undef SCAN_STEP
#undef SDOT

  // epilogue: emission for the last h (in hls0)
  if (eact) {
    const unsigned int* hp = hls0 + eo;
    uint4 e0 = *((const uint4*)hp);
    uint4 e1 = *((const uint4*)(hp + 4));
    uint4 e2 = *((const uint4*)(hp + 8));
    uint4 e3 = *((const uint4*)(hp + 12));
    uint4 e4 = *((const uint4*)(hp + 16));
    uint4 e5 = *((const uint4*)(hp + 20));
    uint2 e6 = *((const uint2*)(hp + 24));
    float a0, a1, a2, a3;
    a0 = fdot2(wt[0], bc_h2(e0.x), 0.f);
    a1 = fdot2(wt[1], bc_h2(e0.y), 0.f);
    a2 = fdot2(wt[2], bc_h2(e0.z), 0.f);
    a3 = fdot2(wt[3], bc_h2(e0.w), 0.f);
    EDOT(4, e1.x)  EDOT(5, e1.y)  EDOT(6, e1.z)  EDOT(7, e1.w)
    EDOT(8, e2.x)  EDOT(9, e2.y)  EDOT(10, e2.z) EDOT(11, e2.w)
    EDOT(12, e3.x) EDOT(13, e3.y) EDOT(14, e3.z) EDOT(15, e3.w)
    EDOT(16, e4.x) EDOT(17, e4.y) EDOT(18, e4.z) EDOT(19, e4.w)
    EDOT(20, e5.x) EDOT(21, e5.y) EDOT(22, e5.z) EDOT(23, e5.w)
    EDOT(24, e6.x) EDOT(25, e6.y)
    float ss = (a0 + a1) + (a2 + a3);
    float tot = qadd<177>(ss);
    if (hf == 0) {
      int ttp = dir ? 0 : (TT - 1);
      emo[((size_t)b * TT + ttp) * LL + l] = tot + bt;
    }
  }
#undef EDOT
}

// ---------------------------------------------------------------------------
// CRF all-in-one v2: block b = batch elem, 192 threads = 3 waves.
// Wave 0 = forward alpha (t=0..255), wave 1 = backward beta (t=511..256),
// wave 2 = gold. Per step the cross-lane broadcast of A = 2^(a-sh) goes
// through a per-wave LDS buffer: 1 ds_write_b32 + 7 ds_read_b128 (broadcast,
// conflict-free) instead of 25 ds_bpermute gathers. Same-wave DS ops are
// in-order; wave_fence pins compiler ordering. Pad slots A[25..27]=0 and
// E[25..27]=0 keep the fma tail exact. atomicAdd(out, logZ - gold);
// d_out pre-zeroed by hipMemsetAsync.
// ---------------------------------------------------------------------------
__global__ __launch_bounds__(192) void crf_all2(
    const float* __restrict__ em_f, const float* __restrict__ em_b,
    const int* __restrict__ tags, const int* __restrict__ lengths,
    const float* __restrict__ trans,
    const float* __restrict__ startt, const float* __restrict__ endt,
    float* __restrict__ out)
{
  const int tid = threadIdx.x;
  const int b   = blockIdx.x;
  const int w   = tid >> 6;
  const int lane = tid & 63;

  __shared__ __align__(16) float As[2][32];
  __shared__ float abf[LL], abb[LL];
  __shared__ float gd;

  if (w < 2 && lane >= LL && lane < 32) As[w][lane] = 0.f;

  if (w < 2) {
    const int side = w;
    const int j = (lane < LL) ? lane : 0;
    const float* ef = em_f + (size_t)b * TT * LL;
    const float* eb = em_b + (size_t)b * TT * LL;
    float* Aw = As[side];
    const float4* Ap = (const float4*)Aw;

    float E[28];
#pragma unroll
    for (int i = 0; i < LL; ++i) {
      float tv = (side == 0 ? trans[i * LL + j] : trans[j * LL + i]);
      E[i] = fexp2(tv * F_LOG2E);
    }
    E[25] = 0.f; E[26] = 0.f; E[27] = 0.f;

#define LSE_STEP(vin, aout)                                                \
    {                                                                      \
      float sh = rfl(vin);                                                 \
      C += sh;                                                             \
      float A = fexp2((vin) - sh);                                         \
      if (lane < LL) Aw[lane] = A;                                         \
      wave_fence();                                                        \
      float4 q0 = Ap[0], q1 = Ap[1], q2 = Ap[2], q3 = Ap[3];               \
      float4 q4 = Ap[4], q5 = Ap[5], q6 = Ap[6];                           \
      float s0, s1, s2, s3;                                                \
      s0 = q0.x * E[0];  s1 = q0.y * E[1];                                 \
      s2 = q0.z * E[2];  s3 = q0.w * E[3];                                 \
      s0 = fmaf(q1.x, E[4], s0);  s1 = fmaf(q1.y, E[5], s1);               \
      s2 = fmaf(q1.z, E[6], s2);  s3 = fmaf(q1.w, E[7], s3);               \
      s0 = fmaf(q2.x, E[8], s0);  s1 = fmaf(q2.y, E[9], s1);               \
      s2 = fmaf(q2.z, E[10], s2); s3 = fmaf(q2.w, E[11], s3);              \
      s0 = fmaf(q3.x, E[12], s0); s1 = fmaf(q3.y, E[13], s1);              \
      s2 = fmaf(q3.z, E[14], s2); s3 = fmaf(q3.w, E[15], s3);              \
      s0 = fmaf(q4.x, E[16], s0); s1 = fmaf(q4.y, E[17], s1);              \
      s2 = fmaf(q4.z, E[18], s2); s3 = fmaf(q4.w, E[19], s3);              \
      s0 = fmaf(q5.x, E[20], s0); s1 = fmaf(q5.y, E[21], s1);              \
      s2 = fmaf(q5.z, E[22], s2); s3 = fmaf(q5.w, E[23], s3);              \
      s0 = fmaf(q6.x, E[24], s0); s1 = fmaf(q6.y, E[25], s1);              \
      s2 = fmaf(q6.z, E[26], s2); s3 = fmaf(q6.w, E[27], s3);              \
      aout = flog2((s0 + s1) + (s2 + s3));                                 \
    }

    float a, C = 0.f;
    if (side == 0) {
      a = (startt[j] + ef[j] + eb[j]) * F_LOG2E;
      float efA = ef[LL + j],     ebA = eb[LL + j];
      float efB = ef[2 * LL + j], ebB = eb[2 * LL + j];
      for (int t = 1; t < 256; ++t) {
        float em2 = (efA + ebA) * F_LOG2E;
        int tn = (t + 2 < 256) ? (t + 2) : 255;
        efA = efB; ebA = ebB;
        efB = ef[(size_t)tn * LL + j];
        ebB = eb[(size_t)tn * LL + j];
        float nx;
        LSE_STEP(a, nx)
        a = nx + em2;
      }
    } else {
      a = endt[j] * F_LOG2E;
      float efA = ef[(size_t)(TT - 1) * LL + j], ebA = eb[(size_t)(TT - 1) * LL + j];
      float efB = ef[(size_t)(TT - 2) * LL + j], ebB = eb[(size_t)(TT - 2) * LL + j];
      for (int stpi = 0; stpi < 256; ++stpi) {
        float em2 = (efA + ebA) * F_LOG2E;
        int t1n = (stpi + 2 < 256) ? (TT - 3 - stpi) : 256;
        efA = efB; ebA = ebB;
        efB = ef[(size_t)t1n * LL + j];
        ebB = eb[(size_t)t1n * LL + j];
        float v = a + em2;
        LSE_STEP(v, a)
      }
    }
#undef LSE_STEP
    if (lane < LL) {
      if (side == 0) abf[lane] = a + C;   // log2 domain
      else          abb[lane] = a + C;
    }
  } else {
    const int len = lengths[b];
    float acc = 0.f;
#pragma unroll
    for (int k = 0; k < 8; ++k) {
      int t = k * 64 + lane;
      int tg = tags[b * TT + t];
      size_t ei = ((size_t)b * TT + t) * LL + tg;
      float e = em_f[ei] + em_b[ei];
      float term;
      if (t == 0) term = startt[tg] + e;
      else        term = trans[tags[b * TT + t - 1] * LL + tg] + e;
      if (t == len - 1) term += endt[tg];
      if (t < len) acc += term;
    }
    for (int o = 32; o > 0; o >>= 1) acc += __shfl_down(acc, o);
    if (lane == 0) gd = acc;
  }
  __syncthreads();

  if (tid < 64) {
    float v = (tid < LL) ? (abf[tid] + abb[tid]) : -1e30f;
    float m = v;
    for (int o = 32; o > 0; o >>= 1) m = fmaxf(m, __shfl_down(m, o));
    m = rfl(m);
    float e = (tid < LL) ? fexp2(v - m) : 0.f;
    for (int o = 32; o > 0; o >>= 1) e += __shfl_down(e, o);
    if (tid == 0)
      atomicAdd(out, (m + flog2(e)) * F_LN2 - gd);
  }
}

extern "C" void kernel_launch(void* const* d_in, const int* in_sizes, int n_in,
                              void* d_out, int out_size, void* d_ws, size_t ws_size,
                              hipStream_t stream) {
  const int*   tok   = (const int*)d_in[0];
  const int*   tags  = (const int*)d_in[1];
  const int*   lens  = (const int*)d_in[2];
  const float* emb   = (const float*)d_in[3];
  const float* wif   = (const float*)d_in[4];
  const float* whf   = (const float*)d_in[5];
  const float* bif   = (const float*)d_in[6];
  const float* bhf   = (const float*)d_in[7];
  const float* wib   = (const float*)d_in[8];
  const float* whb   = (const float*)d_in[9];
  const float* bib   = (const float*)d_in[10];
  const float* bhb   = (const float*)d_in[11];
  const float* wtag  = (const float*)d_in[12];
  const float* btag  = (const float*)d_in[13];
  const float* trans = (const float*)d_in[14];
  const float* st    = (const float*)d_in[15];
  const float* en    = (const float*)d_in[16];

  char* wsb = (char*)d_ws;
  float* em_f = (float*)wsb;                                   //  6,553,600 B
  float* em_b = (float*)(wsb + 6553600);                       //  6,553,600 B

  hipMemsetAsync(d_out, 0, sizeof(float), stream);

  lstm_fused3<<<256, 512, 0, stream>>>(tok, emb, wif, wib, bif, bhf, bib, bhb,
                                       whf, whb, wtag, btag, em_f, em_b);
  crf_all2<<<128, 192, 0, stream>>>(em_f, em_b, tags, lens, trans, st, en,
                                    (float*)d_out);
}